// Round 1
// baseline (665.306 us; speedup 1.0000x reference)
//
#include <hip/hip_runtime.h>
#include <math.h>

#define NB 128   // batch
#define ND 1024  // embed dim
#define NS 14    // sum of K_range
#define NDH 128  // head dim

// s in [0,14) -> group g in [0,4), k within group
__device__ __forceinline__ void s_decomp(int s, int& g, int& k) {
  if (s < 2)      { g = 0; k = s; }
  else if (s < 5) { g = 1; k = s - 2; }
  else if (s < 9) { g = 2; k = s - 5; }
  else            { g = 3; k = s - 9; }
}

__device__ __forceinline__ const float* grp_ptr(int g, const float* p2, const float* p3,
                                                const float* p4, const float* p5) {
  return g == 0 ? p2 : g == 1 ? p3 : g == 2 ? p4 : p5;
}

__device__ __forceinline__ int grp_base(int g) {  // base row in the 112-row table
  return g == 0 ? 0 : g == 1 ? 16 : g == 2 ? 40 : 72;
}
__device__ __forceinline__ int grp_k(int g) { return g + 2; }

// ---------------- K1: distances, argmin per group, cls, counts, repr_sum ----------------
__global__ __launch_bounds__(128) void k_assign(
    const float* __restrict__ x,
    const float* __restrict__ p2, const float* __restrict__ p3,
    const float* __restrict__ p4, const float* __restrict__ p5,
    int* __restrict__ cls, int* __restrict__ counts, float* __restrict__ scal)
{
  __shared__ float xs[ND];
  __shared__ float d2s[112];
  int b = blockIdx.x, t = threadIdx.x;
  for (int i = t; i < ND; i += 128) xs[i] = x[(size_t)b * ND + i];
  __syncthreads();
  if (t < 112) {
    const float* pp; int idx;
    if (t < 16)      { pp = p2; idx = t; }
    else if (t < 40) { pp = p3; idx = t - 16; }
    else if (t < 72) { pp = p4; idx = t - 40; }
    else             { pp = p5; idx = t - 72; }
    const float* pr = pp + (size_t)idx * ND;
    float acc = 0.f;
    for (int d = 0; d < ND; ++d) { float df = xs[d] - pr[d]; acc += df * df; }
    d2s[t] = acc;
  }
  __syncthreads();
  if (t < 4) {
    int base = grp_base(t), kg = grp_k(t), cnt = 8 * kg;
    float mv = d2s[base]; int mi = 0;
    for (int j = 1; j < cnt; ++j) { float v = d2s[base + j]; if (v < mv) { mv = v; mi = j; } }
    int c = mi / kg;
    cls[b * 4 + t] = c;
    atomicAdd(&counts[t * 8 + c], 1);
    atomicAdd(&scal[0], mv);   // repr_sum contribution = min squared distance
  }
}

// ---------------- K2: std_loss partials + M matrix (112 x 1024) ----------------
__global__ __launch_bounds__(256) void k_stats(
    const float* __restrict__ p2, const float* __restrict__ p3,
    const float* __restrict__ p4, const float* __restrict__ p5,
    const int* __restrict__ counts, float* __restrict__ M, float* __restrict__ scal)
{
  int idx = blockIdx.x * 256 + threadIdx.x;   // 56*256 = 14336 = NS*ND exactly
  int s = idx >> 10, d = idx & 1023;
  int g, k; s_decomp(s, g, k);
  const float* pp = grp_ptr(g, p2, p3, p4, p5);
  int kg = grp_k(g);
  float vc[8], nc[8];
  float sum = 0.f, sumsq = 0.f;
#pragma unroll
  for (int c = 0; c < 8; ++c) {
    float v = pp[((size_t)(c * kg + k)) * ND + d];
    float n = (float)counts[g * 8 + c];
    vc[c] = v; nc[c] = n;
    sum += n * v; sumsq += n * v * v;
  }
  float mean = sum * (1.f / 128.f);
  float var = (sumsq - 128.f * mean * mean) * (1.f / 127.f);
  float sd = sqrtf(var + 1e-4f);
#pragma unroll
  for (int c = 0; c < 8; ++c)
    M[((size_t)(s * 8 + c)) * ND + d] = sqrtf(nc[c] * (1.f / 1791.f)) * (vc[c] - mean);
  float part = fmaxf(1.f - sd, 0.f);
  __shared__ float red[256];
  red[threadIdx.x] = part; __syncthreads();
  for (int o = 128; o > 0; o >>= 1) { if (threadIdx.x < o) red[threadIdx.x] += red[threadIdx.x + o]; __syncthreads(); }
  if (threadIdx.x == 0) atomicAdd(&scal[1], red[0]);
}

// ---------------- K3: fro_sum = || M M^T ||_F^2 ----------------
__global__ __launch_bounds__(128) void k_gram(const float* __restrict__ M, float* __restrict__ scal)
{
  __shared__ float mi[ND];
  __shared__ float red[128];
  int i = blockIdx.x, t = threadIdx.x;
  for (int d = t; d < ND; d += 128) mi[d] = M[(size_t)i * ND + d];
  __syncthreads();
  float p = 0.f;
  if (t < 112) {
    const float* mj = M + (size_t)t * ND;
    float acc = 0.f;
    for (int d = 0; d < ND; ++d) acc += mi[d] * mj[d];
    p = acc * acc;
  }
  red[t] = p; __syncthreads();
  for (int o = 64; o > 0; o >>= 1) { if (t < o) red[t] += red[t + o]; __syncthreads(); }
  if (t == 0) atomicAdd(&scal[2], red[0]);
}

// ---------------- K4: diagsq_sum = sum_d (cov_dd)^2 ----------------
__global__ __launch_bounds__(256) void k_diag(const float* __restrict__ M, float* __restrict__ scal)
{
  int d = blockIdx.x * 256 + threadIdx.x;   // 4*256 = 1024
  float tsum = 0.f;
  for (int r = 0; r < 112; ++r) { float v = M[(size_t)r * ND + d]; tsum += v * v; }
  float p = tsum * tsum;
  __shared__ float red[256];
  red[threadIdx.x] = p; __syncthreads();
  for (int o = 128; o > 0; o >>= 1) { if (threadIdx.x < o) red[threadIdx.x] += red[threadIdx.x + o]; __syncthreads(); }
  if (threadIdx.x == 0) atomicAdd(&scal[3], red[0]);
}

// ---------------- K5: LayerNorm of the 112 distinct proto rows (+ raw copy) ----------------
__global__ __launch_bounds__(256) void k_ln(
    const float* __restrict__ p2, const float* __restrict__ p3,
    const float* __restrict__ p4, const float* __restrict__ p5,
    float* __restrict__ xn, float* __restrict__ pall)
{
  int r = blockIdx.x, t = threadIdx.x;
  const float* pp; int idx;
  if (r < 16)      { pp = p2; idx = r; }
  else if (r < 40) { pp = p3; idx = r - 16; }
  else if (r < 72) { pp = p4; idx = r - 40; }
  else             { pp = p5; idx = r - 72; }
  const float* row = pp + (size_t)idx * ND;
  float s1 = 0.f, s2 = 0.f;
  for (int d = t; d < ND; d += 256) { float v = row[d]; s1 += v; s2 += v * v; }
  __shared__ float ra[256], rb[256];
  ra[t] = s1; rb[t] = s2; __syncthreads();
  for (int o = 128; o > 0; o >>= 1) { if (t < o) { ra[t] += ra[t + o]; rb[t] += rb[t + o]; } __syncthreads(); }
  __shared__ float mu, rstd;
  if (t == 0) {
    float m = ra[0] * (1.f / 1024.f);
    float var = rb[0] * (1.f / 1024.f) - m * m;
    mu = m; rstd = rsqrtf(var + 1e-5f);
  }
  __syncthreads();
  for (int d = t; d < ND; d += 256) {
    float v = row[d];
    xn[(size_t)r * ND + d] = (v - mu) * rstd;
    pall[(size_t)r * ND + d] = v;
  }
}

// ---------------- K6: qkv = h_b @ w_qkv[c']^T + b_qkv[c'],  h = xn*ln_g + ln_b ----------------
__global__ __launch_bounds__(256) void k_qkv(
    const float* __restrict__ xn, const int* __restrict__ cls,
    const float* __restrict__ ln_g, const float* __restrict__ ln_b,
    const float* __restrict__ w_qkv, const float* __restrict__ b_qkv,
    float* __restrict__ qkv)
{
  __shared__ float Ht[16 * 36];
  __shared__ float Wt[128 * 36];
  __shared__ int rows[NS];
  int b = blockIdx.y;
  int fbase = blockIdx.x * 128;
  int t = threadIdx.x;
  int cp = cls[b * 4 + 3];
  if (t < NS) {
    int g, k; s_decomp(t, g, k);
    int cg = cls[b * 4 + g];
    rows[t] = grp_base(g) + cg * grp_k(g) + k;
  }
  const float* W  = w_qkv + (size_t)cp * 3072 * ND;
  const float* lg = ln_g + (size_t)cp * ND;
  const float* lb = ln_b + (size_t)cp * ND;
  int f = t & 127, sh = t >> 7;
  float acc[8] = {0.f, 0.f, 0.f, 0.f, 0.f, 0.f, 0.f, 0.f};
  for (int kt = 0; kt < ND; kt += 32) {
    __syncthreads();  // guards rows[] on iter 0, prev compute afterwards
#pragma unroll
    for (int i = 0; i < 2; ++i) {
      int idx = i * 256 + t, kk = idx & 31, ss = idx >> 5;
      float h = 0.f;
      if (ss < NS) {
        int d = kt + kk;
        h = xn[(size_t)rows[ss] * ND + d] * lg[d] + lb[d];
      }
      Ht[ss * 36 + kk] = h;
    }
#pragma unroll
    for (int i = 0; i < 16; ++i) {
      int idx = i * 256 + t, kk = idx & 31, fr = idx >> 5;
      Wt[fr * 36 + kk] = W[(size_t)(fbase + fr) * ND + kt + kk];
    }
    __syncthreads();
#pragma unroll
    for (int kk = 0; kk < 32; kk += 4) {
      float4 w4 = *(const float4*)&Wt[f * 36 + kk];
#pragma unroll
      for (int j = 0; j < 8; ++j) {
        float4 h4 = *(const float4*)&Ht[(sh * 8 + j) * 36 + kk];
        acc[j] += w4.x * h4.x + w4.y * h4.y + w4.z * h4.z + w4.w * h4.w;
      }
    }
  }
  float bq = b_qkv[(size_t)cp * 3072 + fbase + f];
#pragma unroll
  for (int j = 0; j < 8; ++j) {
    int s = sh * 8 + j;
    if (s < NS) qkv[((size_t)b * NS + s) * 3072 + fbase + f] = acc[j] + bq;
  }
}

// ---------------- K7: per (b, head) attention, S=14, dh=128 ----------------
__global__ __launch_bounds__(256) void k_attn(const float* __restrict__ qkv, float* __restrict__ obuf)
{
  __shared__ float qs[NS * NDH], ks[NS * NDH], vs[NS * NDH];
  __shared__ float sc[NS * NS];
  int h = blockIdx.x, b = blockIdx.y, t = threadIdx.x;
  const float scale = 0.08838834764831843f;  // 128^-0.5
  size_t base = (size_t)b * NS * 3072;
  for (int i = t; i < NS * NDH; i += 256) {
    int s = i >> 7, e = i & 127;
    qs[i] = qkv[base + s * 3072 + h * NDH + e] * scale;
    ks[i] = qkv[base + s * 3072 + 1024 + h * NDH + e];
    vs[i] = qkv[base + s * 3072 + 2048 + h * NDH + e];
  }
  __syncthreads();
  if (t < NS * NS) {
    int si = t / NS, sj = t % NS;
    float acc = 0.f;
    for (int e = 0; e < NDH; ++e) acc += qs[si * NDH + e] * ks[sj * NDH + e];
    sc[t] = acc;
  }
  __syncthreads();
  if (t < NS) {
    float m = -1e30f;
    for (int j = 0; j < NS; ++j) m = fmaxf(m, sc[t * NS + j]);
    float e_[NS]; float sum = 0.f;
    for (int j = 0; j < NS; ++j) { float e = expf(sc[t * NS + j] - m); e_[j] = e; sum += e; }
    float inv = 1.f / sum;
    for (int j = 0; j < NS; ++j) sc[t * NS + j] = e_[j] * inv;
  }
  __syncthreads();
  for (int i = t; i < NS * NDH; i += 256) {
    int s = i >> 7, e = i & 127;
    float acc = 0.f;
    for (int j = 0; j < NS; ++j) acc += sc[s * NS + j] * vs[j * NDH + e];
    obuf[((size_t)b * NS + s) * ND + h * NDH + e] = acc;
  }
}

// ---------------- K8: proj + bias + residual ----------------
__global__ __launch_bounds__(256) void k_proj(
    const float* __restrict__ obuf, const int* __restrict__ cls,
    const float* __restrict__ w_proj, const float* __restrict__ b_proj,
    const float* __restrict__ pall, float* __restrict__ att)
{
  __shared__ float Ht[16 * 36];
  __shared__ float Wt[128 * 36];
  __shared__ int rows[NS];
  int b = blockIdx.y;
  int fbase = blockIdx.x * 128;
  int t = threadIdx.x;
  int cp = cls[b * 4 + 3];
  if (t < NS) {
    int g, k; s_decomp(t, g, k);
    int cg = cls[b * 4 + g];
    rows[t] = grp_base(g) + cg * grp_k(g) + k;
  }
  const float* W = w_proj + (size_t)cp * ND * ND;
  int f = t & 127, sh = t >> 7;
  float acc[8] = {0.f, 0.f, 0.f, 0.f, 0.f, 0.f, 0.f, 0.f};
  for (int kt = 0; kt < ND; kt += 32) {
    __syncthreads();
#pragma unroll
    for (int i = 0; i < 2; ++i) {
      int idx = i * 256 + t, kk = idx & 31, ss = idx >> 5;
      Ht[ss * 36 + kk] = (ss < NS) ? obuf[((size_t)b * NS + ss) * ND + kt + kk] : 0.f;
    }
#pragma unroll
    for (int i = 0; i < 16; ++i) {
      int idx = i * 256 + t, kk = idx & 31, fr = idx >> 5;
      Wt[fr * 36 + kk] = W[(size_t)(fbase + fr) * ND + kt + kk];
    }
    __syncthreads();
#pragma unroll
    for (int kk = 0; kk < 32; kk += 4) {
      float4 w4 = *(const float4*)&Wt[f * 36 + kk];
#pragma unroll
      for (int j = 0; j < 8; ++j) {
        float4 h4 = *(const float4*)&Ht[(sh * 8 + j) * 36 + kk];
        acc[j] += w4.x * h4.x + w4.y * h4.y + w4.z * h4.z + w4.w * h4.w;
      }
    }
  }
  float bp = b_proj[(size_t)cp * ND + fbase + f];
#pragma unroll
  for (int j = 0; j < 8; ++j) {
    int s = sh * 8 + j;
    if (s < NS) {
      float res = pall[(size_t)rows[s] * ND + fbase + f];
      att[((size_t)b * NS + s) * ND + fbase + f] = acc[j] + bp + res;
    }
  }
}

// ---------------- K9: normalize rows, pool, logits; write vcr ----------------
__global__ __launch_bounds__(256) void k_final(
    const float* __restrict__ att, const float* __restrict__ w_cls,
    const float* __restrict__ b_cls, const float* __restrict__ scal,
    float* __restrict__ out)
{
  int b = blockIdx.x, t = threadIdx.x;
  __shared__ float red[256];
  __shared__ float inv[NS];
  __shared__ float pooled[ND];
  for (int s = 0; s < NS; ++s) {
    float p = 0.f;
    for (int d = t; d < ND; d += 256) { float v = att[((size_t)b * NS + s) * ND + d]; p += v * v; }
    red[t] = p; __syncthreads();
    for (int o = 128; o > 0; o >>= 1) { if (t < o) red[t] += red[t + o]; __syncthreads(); }
    if (t == 0) inv[s] = 1.f / fmaxf(sqrtf(red[0]), 1e-12f);
    __syncthreads();
  }
  for (int d = t; d < ND; d += 256) {
    float acc = 0.f;
    for (int s = 0; s < NS; ++s) acc += att[((size_t)b * NS + s) * ND + d] * inv[s];
    pooled[d] = acc * (1.f / 14.f);
  }
  __syncthreads();
  int c = t >> 5, lane = t & 31;
  float acc = 0.f;
  for (int d = lane; d < ND; d += 32) acc += pooled[d] * w_cls[(size_t)c * ND + d];
  for (int o = 16; o > 0; o >>= 1) acc += __shfl_down(acc, o, 32);
  if (lane == 0) out[b * 8 + c] = acc + b_cls[c];
  if (b == 0 && t == 0) {
    float repr = scal[0] * (1.f / (128.f * 4.f * 1024.f));
    float stdl = scal[1] * (1.f / 14336.f);
    float covl = (scal[2] - scal[3]) * (1.f / 1024.f);
    out[1024] = 25.f * repr + 25.f * stdl + covl;
  }
}

extern "C" void kernel_launch(void* const* d_in, const int* in_sizes, int n_in,
                              void* d_out, int out_size, void* d_ws, size_t ws_size,
                              hipStream_t stream) {
  const float* x      = (const float*)d_in[0];
  const float* p2     = (const float*)d_in[1];
  const float* p3     = (const float*)d_in[2];
  const float* p4     = (const float*)d_in[3];
  const float* p5     = (const float*)d_in[4];
  const float* ln_g   = (const float*)d_in[5];
  const float* ln_b   = (const float*)d_in[6];
  const float* w_qkv  = (const float*)d_in[7];
  const float* b_qkv  = (const float*)d_in[8];
  const float* w_proj = (const float*)d_in[9];
  const float* b_proj = (const float*)d_in[10];
  const float* w_cls  = (const float*)d_in[11];
  const float* b_cls  = (const float*)d_in[12];
  float* out = (float*)d_out;
  char* ws = (char*)d_ws;

  float* scal   = (float*)(ws + 0);        // [0]=repr [1]=std [2]=fro [3]=diagsq
  int*   counts = (int*)(ws + 64);         // [4][8]
  int*   cls    = (int*)(ws + 256);        // [128][4]
  float* M      = (float*)(ws + 4096);     // 112*1024
  float* xn     = (float*)(ws + 462848);   // 112*1024
  float* pall   = (float*)(ws + 921600);   // 112*1024
  float* qkv    = (float*)(ws + 1380352);  // 128*14*3072
  float* obuf   = (float*)(ws + 23400448); // 128*14*1024
  float* att    = (float*)(ws + 30740480); // 128*14*1024  (ends ~38.1 MB)

  hipMemsetAsync(ws, 0, 256, stream);      // zero scal + counts every call
  k_assign<<<128, 128, 0, stream>>>(x, p2, p3, p4, p5, cls, counts, scal);
  k_stats<<<56, 256, 0, stream>>>(p2, p3, p4, p5, counts, M, scal);
  k_gram<<<112, 128, 0, stream>>>(M, scal);
  k_diag<<<4, 256, 0, stream>>>(M, scal);
  k_ln<<<112, 256, 0, stream>>>(p2, p3, p4, p5, xn, pall);
  k_qkv<<<dim3(24, 128), 256, 0, stream>>>(xn, cls, ln_g, ln_b, w_qkv, b_qkv, qkv);
  k_attn<<<dim3(8, 128), 256, 0, stream>>>(qkv, obuf);
  k_proj<<<dim3(8, 128), 256, 0, stream>>>(obuf, cls, w_proj, b_proj, pall, att);
  k_final<<<128, 256, 0, stream>>>(att, w_cls, b_cls, scal, out);
}

// Round 2
// 296.257 us; speedup vs baseline: 2.2457x; 2.2457x over previous
//
#include <hip/hip_runtime.h>
#include <math.h>

#define NB 128   // batch
#define ND 1024  // embed dim
#define NS 14    // sum of K_range
#define NDH 128  // head dim
#define LDP 72   // padded LDS row stride (bf16 elems): 144 B, 16B-aligned, ~2-way banks

typedef float f32x4 __attribute__((ext_vector_type(4)));
typedef short bf16x8 __attribute__((ext_vector_type(8)));   // 8 bf16 in 4 VGPRs

__device__ __forceinline__ unsigned short f2bf(float v) {   // RNE, finite inputs
  unsigned int u = __builtin_bit_cast(unsigned int, v);
  return (unsigned short)((u + 0x7FFFu + ((u >> 16) & 1u)) >> 16);
}

// s in [0,14) -> group g in [0,4), k within group
__device__ __forceinline__ void s_decomp(int s, int& g, int& k) {
  if (s < 2)      { g = 0; k = s; }
  else if (s < 5) { g = 1; k = s - 2; }
  else if (s < 9) { g = 2; k = s - 5; }
  else            { g = 3; k = s - 9; }
}
__device__ __forceinline__ const float* grp_ptr(int g, const float* p2, const float* p3,
                                                const float* p4, const float* p5) {
  return g == 0 ? p2 : g == 1 ? p3 : g == 2 ? p4 : p5;
}
__device__ __forceinline__ int grp_base(int g) { return g == 0 ? 0 : g == 1 ? 16 : g == 2 ? 40 : 72; }
__device__ __forceinline__ int grp_k(int g) { return g + 2; }

// ---------------- K1: distances, argmin, cls, rows_g, class compaction, repr_sum ----------------
__global__ __launch_bounds__(128) void k_assign(
    const float* __restrict__ x,
    const float* __restrict__ p2, const float* __restrict__ p3,
    const float* __restrict__ p4, const float* __restrict__ p5,
    int* __restrict__ cls, int* __restrict__ counts, float* __restrict__ scal,
    int* __restrict__ rows_g, int* __restrict__ ccnt, int* __restrict__ order)
{
  __shared__ float xs[ND];
  __shared__ float d2s[112];
  __shared__ int cls_s[4];
  int b = blockIdx.x, t = threadIdx.x;
  for (int i = t; i < ND; i += 128) xs[i] = x[(size_t)b * ND + i];
  __syncthreads();
  if (t < 112) {
    const float* pp; int idx;
    if (t < 16)      { pp = p2; idx = t; }
    else if (t < 40) { pp = p3; idx = t - 16; }
    else if (t < 72) { pp = p4; idx = t - 40; }
    else             { pp = p5; idx = t - 72; }
    const float* pr = pp + (size_t)idx * ND;
    float acc = 0.f;
    for (int d = 0; d < ND; ++d) { float df = xs[d] - pr[d]; acc += df * df; }
    d2s[t] = acc;
  }
  __syncthreads();
  if (t < 4) {
    int base = grp_base(t), kg = grp_k(t), cnt = 8 * kg;
    float mv = d2s[base]; int mi = 0;
    for (int j = 1; j < cnt; ++j) { float v = d2s[base + j]; if (v < mv) { mv = v; mi = j; } }
    int c = mi / kg;
    cls[b * 4 + t] = c; cls_s[t] = c;
    atomicAdd(&counts[t * 8 + c], 1);
    atomicAdd(&scal[0], mv);
  }
  __syncthreads();
  if (t < NS) {
    int g, k; s_decomp(t, g, k);
    rows_g[b * NS + t] = grp_base(g) + cls_s[g] * grp_k(g) + k;
  }
  if (t == 0) {
    int cp = cls_s[3];
    int pos = atomicAdd(&ccnt[cp], 1);
    order[cp * 128 + pos] = b;
  }
}

// ---------------- K2: std_loss partials + M matrix (112 x 1024) ----------------
__global__ __launch_bounds__(256) void k_stats(
    const float* __restrict__ p2, const float* __restrict__ p3,
    const float* __restrict__ p4, const float* __restrict__ p5,
    const int* __restrict__ counts, float* __restrict__ M, float* __restrict__ scal)
{
  int idx = blockIdx.x * 256 + threadIdx.x;   // 56*256 = 14336 = NS*ND
  int s = idx >> 10, d = idx & 1023;
  int g, k; s_decomp(s, g, k);
  const float* pp = grp_ptr(g, p2, p3, p4, p5);
  int kg = grp_k(g);
  float vc[8], nc[8];
  float sum = 0.f, sumsq = 0.f;
#pragma unroll
  for (int c = 0; c < 8; ++c) {
    float v = pp[((size_t)(c * kg + k)) * ND + d];
    float n = (float)counts[g * 8 + c];
    vc[c] = v; nc[c] = n;
    sum += n * v; sumsq += n * v * v;
  }
  float mean = sum * (1.f / 128.f);
  float var = (sumsq - 128.f * mean * mean) * (1.f / 127.f);
  float sd = sqrtf(var + 1e-4f);
#pragma unroll
  for (int c = 0; c < 8; ++c)
    M[((size_t)(s * 8 + c)) * ND + d] = sqrtf(nc[c] * (1.f / 1791.f)) * (vc[c] - mean);
  float part = fmaxf(1.f - sd, 0.f);
  __shared__ float red[256];
  red[threadIdx.x] = part; __syncthreads();
  for (int o = 128; o > 0; o >>= 1) { if (threadIdx.x < o) red[threadIdx.x] += red[threadIdx.x + o]; __syncthreads(); }
  if (threadIdx.x == 0) atomicAdd(&scal[1], red[0]);
}

// ---------------- K3: fro_sum = || M M^T ||_F^2 ----------------
__global__ __launch_bounds__(128) void k_gram(const float* __restrict__ M, float* __restrict__ scal)
{
  __shared__ float mi[ND];
  __shared__ float red[128];
  int i = blockIdx.x, t = threadIdx.x;
  for (int d = t; d < ND; d += 128) mi[d] = M[(size_t)i * ND + d];
  __syncthreads();
  float p = 0.f;
  if (t < 112) {
    const float* mj = M + (size_t)t * ND;
    float acc = 0.f;
    for (int d = 0; d < ND; ++d) acc += mi[d] * mj[d];
    p = acc * acc;
  }
  red[t] = p; __syncthreads();
  for (int o = 64; o > 0; o >>= 1) { if (t < o) red[t] += red[t + o]; __syncthreads(); }
  if (t == 0) atomicAdd(&scal[2], red[0]);
}

// ---------------- K4: diagsq_sum ----------------
__global__ __launch_bounds__(256) void k_diag(const float* __restrict__ M, float* __restrict__ scal)
{
  int d = blockIdx.x * 256 + threadIdx.x;
  float tsum = 0.f;
  for (int r = 0; r < 112; ++r) { float v = M[(size_t)r * ND + d]; tsum += v * v; }
  float p = tsum * tsum;
  __shared__ float red[256];
  red[threadIdx.x] = p; __syncthreads();
  for (int o = 128; o > 0; o >>= 1) { if (threadIdx.x < o) red[threadIdx.x] += red[threadIdx.x + o]; __syncthreads(); }
  if (threadIdx.x == 0) atomicAdd(&scal[3], red[0]);
}

// ---------------- K5: LayerNorm of 112 proto rows -> h_bf[8][112][1024] bf16, + raw copy ----------------
__global__ __launch_bounds__(256) void k_ln(
    const float* __restrict__ p2, const float* __restrict__ p3,
    const float* __restrict__ p4, const float* __restrict__ p5,
    const float* __restrict__ ln_g, const float* __restrict__ ln_b,
    unsigned short* __restrict__ hbf, float* __restrict__ pall)
{
  int r = blockIdx.x, t = threadIdx.x;
  const float* pp; int idx;
  if (r < 16)      { pp = p2; idx = r; }
  else if (r < 40) { pp = p3; idx = r - 16; }
  else if (r < 72) { pp = p4; idx = r - 40; }
  else             { pp = p5; idx = r - 72; }
  const float* row = pp + (size_t)idx * ND;
  __shared__ float xs[ND];
  float s1 = 0.f, s2 = 0.f;
  for (int d = t; d < ND; d += 256) { float v = row[d]; xs[d] = v; s1 += v; s2 += v * v; }
  __shared__ float ra[256], rb[256];
  ra[t] = s1; rb[t] = s2; __syncthreads();
  for (int o = 128; o > 0; o >>= 1) { if (t < o) { ra[t] += ra[t + o]; rb[t] += rb[t + o]; } __syncthreads(); }
  __shared__ float mu, rstd;
  if (t == 0) {
    float m = ra[0] * (1.f / 1024.f);
    float var = rb[0] * (1.f / 1024.f) - m * m;
    mu = m; rstd = rsqrtf(var + 1e-5f);
  }
  __syncthreads();
  for (int d = t; d < ND; d += 256) pall[(size_t)r * ND + d] = xs[d];
#pragma unroll
  for (int c = 0; c < 8; ++c)
    for (int d = t; d < ND; d += 256) {
      float h = (xs[d] - mu) * rstd * ln_g[(size_t)c * ND + d] + ln_b[(size_t)c * ND + d];
      hbf[((size_t)(c * 112 + r)) * ND + d] = f2bf(h);
    }
}

// ---------------- K6: qkv_all[c] = H_bf[c] @ W_qkv[c]^T + b  (8 x [112 x 3072]) ----------------
__global__ __launch_bounds__(256) void k_qkv_mfma(
    const unsigned short* __restrict__ hbf, const float* __restrict__ w_qkv,
    const float* __restrict__ b_qkv, float* __restrict__ qkv_all)
{
  __shared__ unsigned short Hl[112 * LDP];
  __shared__ unsigned short Wl[64 * LDP];
  int c = blockIdx.y;
  int nb0 = blockIdx.x * 64;
  int t = threadIdx.x, lane = t & 63, wv = t >> 6;
  const float* W = w_qkv + ((size_t)c * 3072 + nb0) * 1024;
  const unsigned short* H = hbf + (size_t)c * 112 * 1024;
  f32x4 acc[7] = {};
  int r16 = lane & 15, kq = (lane >> 4) * 8;
  for (int kt = 0; kt < 1024; kt += 64) {
    __syncthreads();
    for (int i = t; i < 896; i += 256) {            // H: 112x64 bf16, 16B chunks
      int r = i >> 3, kc = (i & 7) * 8;
      *(uint4*)&Hl[r * LDP + kc] = *(const uint4*)(H + (size_t)r * 1024 + kt + kc);
    }
    for (int i = t; i < 1024; i += 256) {           // W: 64x64 fp32 -> bf16
      int r = i >> 4, kc = (i & 15) * 4;
      float4 f = *(const float4*)(W + (size_t)r * 1024 + kt + kc);
      ushort4 u4; u4.x = f2bf(f.x); u4.y = f2bf(f.y); u4.z = f2bf(f.z); u4.w = f2bf(f.w);
      *(ushort4*)&Wl[r * LDP + kc] = u4;
    }
    __syncthreads();
#pragma unroll
    for (int kk = 0; kk < 64; kk += 32) {
      bf16x8 bv = *(const bf16x8*)&Wl[(wv * 16 + r16) * LDP + kk + kq];
#pragma unroll
      for (int m = 0; m < 7; ++m) {
        bf16x8 av = *(const bf16x8*)&Hl[(m * 16 + r16) * LDP + kk + kq];
        acc[m] = __builtin_amdgcn_mfma_f32_16x16x32_bf16(av, bv, acc[m], 0, 0, 0);
      }
    }
  }
  int col = nb0 + wv * 16 + r16;
  float bq = b_qkv[(size_t)c * 3072 + col];
  int rbase = (lane >> 4) * 4;
#pragma unroll
  for (int m = 0; m < 7; ++m)
#pragma unroll
    for (int r = 0; r < 4; ++r)
      qkv_all[((size_t)c * 112 + m * 16 + rbase + r) * 3072 + col] = acc[m][r] + bq;
}

// ---------------- K7: attention per (head, sample), gathering from qkv_all ----------------
__global__ __launch_bounds__(256) void k_attn(
    const float* __restrict__ qkv_all, const int* __restrict__ cls,
    const int* __restrict__ rows_g, float* __restrict__ obuf)
{
  __shared__ float qs[NS * NDH], ks2[NS * NDH], vs[NS * NDH];
  __shared__ float sc[NS * NS];
  __shared__ int rg[NS];
  int h = blockIdx.x, b = blockIdx.y, t = threadIdx.x;
  if (t < NS) rg[t] = rows_g[b * NS + t];
  __syncthreads();
  int cp = cls[b * 4 + 3];
  const float scale = 0.08838834764831843f;  // 128^-0.5
  for (int i = t; i < NS * NDH; i += 256) {
    int s = i >> 7, e = i & 127;
    size_t base = ((size_t)cp * 112 + rg[s]) * 3072 + h * NDH + e;
    qs[i] = qkv_all[base] * scale;
    ks2[i] = qkv_all[base + 1024];
    vs[i] = qkv_all[base + 2048];
  }
  __syncthreads();
  if (t < NS * NS) {
    int si = t / NS, sj = t % NS;
    float acc = 0.f;
    for (int e = 0; e < NDH; ++e) acc += qs[si * NDH + e] * ks2[sj * NDH + e];
    sc[t] = acc;
  }
  __syncthreads();
  if (t < NS) {
    float m = -1e30f;
    for (int j = 0; j < NS; ++j) m = fmaxf(m, sc[t * NS + j]);
    float e_[NS]; float sum = 0.f;
    for (int j = 0; j < NS; ++j) { float e = expf(sc[t * NS + j] - m); e_[j] = e; sum += e; }
    float inv = 1.f / sum;
    for (int j = 0; j < NS; ++j) sc[t * NS + j] = e_[j] * inv;
  }
  __syncthreads();
  for (int i = t; i < NS * NDH; i += 256) {
    int s = i >> 7, e = i & 127;
    float acc = 0.f;
    for (int j = 0; j < NS; ++j) acc += sc[s * NS + j] * vs[j * NDH + e];
    obuf[((size_t)b * NS + s) * ND + h * NDH + e] = acc;
  }
}

// ---------------- K8: proj, class-batched (8 samples x 14 rows = M 112 per block) ----------------
__global__ __launch_bounds__(256) void k_proj_mfma(
    const float* __restrict__ obuf, const int* __restrict__ order,
    const int* __restrict__ ccnt, const int* __restrict__ rows_g,
    const float* __restrict__ w_proj, const float* __restrict__ b_proj,
    const float* __restrict__ pall, float* __restrict__ att)
{
  int c = blockIdx.y >> 4, ch = blockIdx.y & 15;
  int cnt = ccnt[c];
  int nb = cnt - ch * 8;
  if (nb <= 0) return;
  if (nb > 8) nb = 8;
  __shared__ unsigned short Al[112 * LDP];
  __shared__ unsigned short Wl[128 * LDP];
  __shared__ int sid[8];
  int t = threadIdx.x, lane = t & 63, wv = t >> 6;
  if (t < 8) sid[t] = order[c * 128 + ch * 8 + ((t < nb) ? t : 0)];
  int nb0 = blockIdx.x * 128;
  const float* W = w_proj + ((size_t)c * 1024 + nb0) * 1024;
  f32x4 acc[7][2] = {};
  int r16 = lane & 15, kq = (lane >> 4) * 8;
  for (int kt = 0; kt < 1024; kt += 64) {
    __syncthreads();   // iter 0: guards sid[]
    for (int i = t; i < 1792; i += 256) {           // A: 112x64 fp32 -> bf16 (8 samples x 14 rows)
      int r = i >> 4, kc = (i & 15) * 4;
      int si = r / 14, s = r - si * 14;
      float4 f = *(const float4*)(obuf + ((size_t)sid[si] * NS + s) * 1024 + kt + kc);
      ushort4 u4; u4.x = f2bf(f.x); u4.y = f2bf(f.y); u4.z = f2bf(f.z); u4.w = f2bf(f.w);
      *(ushort4*)&Al[r * LDP + kc] = u4;
    }
    for (int i = t; i < 2048; i += 256) {           // W: 128x64 fp32 -> bf16
      int r = i >> 4, kc = (i & 15) * 4;
      float4 f = *(const float4*)(W + (size_t)r * 1024 + kt + kc);
      ushort4 u4; u4.x = f2bf(f.x); u4.y = f2bf(f.y); u4.z = f2bf(f.z); u4.w = f2bf(f.w);
      *(ushort4*)&Wl[r * LDP + kc] = u4;
    }
    __syncthreads();
#pragma unroll
    for (int kk = 0; kk < 64; kk += 32) {
      bf16x8 bv0 = *(const bf16x8*)&Wl[(wv * 32 + r16) * LDP + kk + kq];
      bf16x8 bv1 = *(const bf16x8*)&Wl[(wv * 32 + 16 + r16) * LDP + kk + kq];
#pragma unroll
      for (int m = 0; m < 7; ++m) {
        bf16x8 av = *(const bf16x8*)&Al[(m * 16 + r16) * LDP + kk + kq];
        acc[m][0] = __builtin_amdgcn_mfma_f32_16x16x32_bf16(av, bv0, acc[m][0], 0, 0, 0);
        acc[m][1] = __builtin_amdgcn_mfma_f32_16x16x32_bf16(av, bv1, acc[m][1], 0, 0, 0);
      }
    }
  }
  int rbase = (lane >> 4) * 4;
#pragma unroll
  for (int n = 0; n < 2; ++n) {
    int col = nb0 + wv * 32 + n * 16 + r16;
    float bp = b_proj[(size_t)c * 1024 + col];
#pragma unroll
    for (int m = 0; m < 7; ++m)
#pragma unroll
      for (int r = 0; r < 4; ++r) {
        int row = m * 16 + rbase + r;
        int si = row / 14, s = row - si * 14;
        if (si < nb) {
          int b = sid[si];
          float res = pall[(size_t)rows_g[b * NS + s] * 1024 + col];
          att[((size_t)b * NS + s) * 1024 + col] = acc[m][n][r] + bp + res;
        }
      }
  }
}

// ---------------- K9: normalize rows, pool, logits; write vcr ----------------
__global__ __launch_bounds__(256) void k_final(
    const float* __restrict__ att, const float* __restrict__ w_cls,
    const float* __restrict__ b_cls, const float* __restrict__ scal,
    float* __restrict__ out)
{
  int b = blockIdx.x, t = threadIdx.x;
  __shared__ float red[256];
  __shared__ float inv[NS];
  __shared__ float pooled[ND];
  for (int s = 0; s < NS; ++s) {
    float p = 0.f;
    for (int d = t; d < ND; d += 256) { float v = att[((size_t)b * NS + s) * ND + d]; p += v * v; }
    red[t] = p; __syncthreads();
    for (int o = 128; o > 0; o >>= 1) { if (t < o) red[t] += red[t + o]; __syncthreads(); }
    if (t == 0) inv[s] = 1.f / fmaxf(sqrtf(red[0]), 1e-12f);
    __syncthreads();
  }
  for (int d = t; d < ND; d += 256) {
    float acc = 0.f;
    for (int s = 0; s < NS; ++s) acc += att[((size_t)b * NS + s) * ND + d] * inv[s];
    pooled[d] = acc * (1.f / 14.f);
  }
  __syncthreads();
  int c = t >> 5, lane = t & 31;
  float acc = 0.f;
  for (int d = lane; d < ND; d += 32) acc += pooled[d] * w_cls[(size_t)c * ND + d];
  for (int o = 16; o > 0; o >>= 1) acc += __shfl_down(acc, o, 32);
  if (lane == 0) out[b * 8 + c] = acc + b_cls[c];
  if (b == 0 && t == 0) {
    float repr = scal[0] * (1.f / (128.f * 4.f * 1024.f));
    float stdl = scal[1] * (1.f / 14336.f);
    float covl = (scal[2] - scal[3]) * (1.f / 1024.f);
    out[1024] = 25.f * repr + 25.f * stdl + covl;
  }
}

extern "C" void kernel_launch(void* const* d_in, const int* in_sizes, int n_in,
                              void* d_out, int out_size, void* d_ws, size_t ws_size,
                              hipStream_t stream) {
  const float* x      = (const float*)d_in[0];
  const float* p2     = (const float*)d_in[1];
  const float* p3     = (const float*)d_in[2];
  const float* p4     = (const float*)d_in[3];
  const float* p5     = (const float*)d_in[4];
  const float* ln_g   = (const float*)d_in[5];
  const float* ln_b   = (const float*)d_in[6];
  const float* w_qkv  = (const float*)d_in[7];
  const float* b_qkv  = (const float*)d_in[8];
  const float* w_proj = (const float*)d_in[9];
  const float* b_proj = (const float*)d_in[10];
  const float* w_cls  = (const float*)d_in[11];
  const float* b_cls  = (const float*)d_in[12];
  float* out = (float*)d_out;
  char* ws = (char*)d_ws;

  float* scal   = (float*)(ws + 0);            // [0]=repr [1]=std [2]=fro [3]=diagsq
  int*   counts = (int*)(ws + 64);             // [4][8]
  int*   ccnt   = (int*)(ws + 192);            // [8]
  int*   cls    = (int*)(ws + 256);            // [128][4]
  int*   rows_g = (int*)(ws + 2304);           // [128][14]
  int*   order  = (int*)(ws + 9472);           // [8][128]
  float* pall   = (float*)(ws + 16384);        // 112*1024               -> 475,136
  unsigned short* hbf = (unsigned short*)(ws + 475136);  // 8*112*1024 bf16 -> 2,310,144
  float* qkv_all = (float*)(ws + 2310144);     // 8*112*3072             -> 13,320,192
  float* obuf   = (float*)(ws + 13320192);     // 128*14*1024            -> 20,660,224
  float* att    = (float*)(ws + 20660224);     // 128*14*1024            -> 28,000,256
  float* M      = (float*)(ws + 20660224);     // 112*1024, overlaps att (dead after k_diag)

  hipMemsetAsync(ws, 0, 256, stream);          // scal + counts + ccnt
  k_assign<<<128, 128, 0, stream>>>(x, p2, p3, p4, p5, cls, counts, scal, rows_g, ccnt, order);
  k_stats<<<56, 256, 0, stream>>>(p2, p3, p4, p5, counts, M, scal);
  k_gram<<<112, 128, 0, stream>>>(M, scal);
  k_diag<<<4, 256, 0, stream>>>(M, scal);
  k_ln<<<112, 256, 0, stream>>>(p2, p3, p4, p5, ln_g, ln_b, hbf, pall);
  k_qkv_mfma<<<dim3(48, 8), 256, 0, stream>>>(hbf, w_qkv, b_qkv, qkv_all);
  k_attn<<<dim3(8, 128), 256, 0, stream>>>(qkv_all, cls, rows_g, obuf);
  k_proj_mfma<<<dim3(8, 128), 256, 0, stream>>>(obuf, order, ccnt, rows_g, w_proj, b_proj, pall, att);
  k_final<<<128, 256, 0, stream>>>(att, w_cls, b_cls, scal, out);
}

// Round 3
// 177.609 us; speedup vs baseline: 3.7459x; 1.6680x over previous
//
#include <hip/hip_runtime.h>
#include <math.h>

#define NB 128   // batch
#define ND 1024  // embed dim
#define NS 14    // sum of K_range
#define NDH 128  // head dim

typedef float f32x4 __attribute__((ext_vector_type(4)));
typedef short bf16x8 __attribute__((ext_vector_type(8)));   // 8 bf16 in 4 VGPRs

__device__ __forceinline__ unsigned short f2bf(float v) {   // RNE, finite inputs
  unsigned int u = __builtin_bit_cast(unsigned int, v);
  return (unsigned short)((u + 0x7FFFu + ((u >> 16) & 1u)) >> 16);
}

__device__ __forceinline__ void gl_lds16(const void* g, void* l) {
  __builtin_amdgcn_global_load_lds(
      (const __attribute__((address_space(1))) void*)g,
      (__attribute__((address_space(3))) void*)l, 16, 0, 0);
}

// s in [0,14) -> group g in [0,4), k within group
__device__ __forceinline__ void s_decomp(int s, int& g, int& k) {
  if (s < 2)      { g = 0; k = s; }
  else if (s < 5) { g = 1; k = s - 2; }
  else if (s < 9) { g = 2; k = s - 5; }
  else            { g = 3; k = s - 9; }
}
__device__ __forceinline__ const float* grp_ptr(int g, const float* p2, const float* p3,
                                                const float* p4, const float* p5) {
  return g == 0 ? p2 : g == 1 ? p3 : g == 2 ? p4 : p5;
}
__device__ __forceinline__ int grp_base(int g) { return g == 0 ? 0 : g == 1 ? 16 : g == 2 ? 40 : 72; }
__device__ __forceinline__ int grp_k(int g) { return g + 2; }

// ---------------- K1: distances, argmin, cls, rows_g, class compaction, repr_sum ----------------
__global__ __launch_bounds__(128) void k_assign(
    const float* __restrict__ x,
    const float* __restrict__ p2, const float* __restrict__ p3,
    const float* __restrict__ p4, const float* __restrict__ p5,
    int* __restrict__ cls, int* __restrict__ counts, float* __restrict__ scal,
    int* __restrict__ rows_g, int* __restrict__ ccnt, int* __restrict__ order)
{
  __shared__ float xs[ND];
  __shared__ float d2s[112];
  __shared__ int cls_s[4];
  int b = blockIdx.x, t = threadIdx.x;
  for (int i = t; i < ND; i += 128) xs[i] = x[(size_t)b * ND + i];
  __syncthreads();
  if (t < 112) {
    const float* pp; int idx;
    if (t < 16)      { pp = p2; idx = t; }
    else if (t < 40) { pp = p3; idx = t - 16; }
    else if (t < 72) { pp = p4; idx = t - 40; }
    else             { pp = p5; idx = t - 72; }
    const float* pr = pp + (size_t)idx * ND;
    float acc = 0.f;
    for (int d = 0; d < ND; ++d) { float df = xs[d] - pr[d]; acc += df * df; }
    d2s[t] = acc;
  }
  __syncthreads();
  if (t < 4) {
    int base = grp_base(t), kg = grp_k(t), cnt = 8 * kg;
    float mv = d2s[base]; int mi = 0;
    for (int j = 1; j < cnt; ++j) { float v = d2s[base + j]; if (v < mv) { mv = v; mi = j; } }
    int c = mi / kg;
    cls[b * 4 + t] = c; cls_s[t] = c;
    atomicAdd(&counts[t * 8 + c], 1);
    atomicAdd(&scal[0], mv);
  }
  __syncthreads();
  if (t < NS) {
    int g, k; s_decomp(t, g, k);
    rows_g[b * NS + t] = grp_base(g) + cls_s[g] * grp_k(g) + k;
  }
  if (t == 0) {
    int cp = cls_s[3];
    int pos = atomicAdd(&ccnt[cp], 1);
    order[cp * 128 + pos] = b;
  }
}

// ---------------- K2: std_loss partials + M matrix (112 x 1024) ----------------
__global__ __launch_bounds__(256) void k_stats(
    const float* __restrict__ p2, const float* __restrict__ p3,
    const float* __restrict__ p4, const float* __restrict__ p5,
    const int* __restrict__ counts, float* __restrict__ M, float* __restrict__ scal)
{
  int idx = blockIdx.x * 256 + threadIdx.x;   // 56*256 = 14336 = NS*ND
  int s = idx >> 10, d = idx & 1023;
  int g, k; s_decomp(s, g, k);
  const float* pp = grp_ptr(g, p2, p3, p4, p5);
  int kg = grp_k(g);
  float vc[8], nc[8];
  float sum = 0.f, sumsq = 0.f;
#pragma unroll
  for (int c = 0; c < 8; ++c) {
    float v = pp[((size_t)(c * kg + k)) * ND + d];
    float n = (float)counts[g * 8 + c];
    vc[c] = v; nc[c] = n;
    sum += n * v; sumsq += n * v * v;
  }
  float mean = sum * (1.f / 128.f);
  float var = (sumsq - 128.f * mean * mean) * (1.f / 127.f);
  float sd = sqrtf(var + 1e-4f);
#pragma unroll
  for (int c = 0; c < 8; ++c)
    M[((size_t)(s * 8 + c)) * ND + d] = sqrtf(nc[c] * (1.f / 1791.f)) * (vc[c] - mean);
  float part = fmaxf(1.f - sd, 0.f);
  __shared__ float red[256];
  red[threadIdx.x] = part; __syncthreads();
  for (int o = 128; o > 0; o >>= 1) { if (threadIdx.x < o) red[threadIdx.x] += red[threadIdx.x + o]; __syncthreads(); }
  if (threadIdx.x == 0) atomicAdd(&scal[1], red[0]);
}

// ---------------- K3: fro_sum = || M M^T ||_F^2 ----------------
__global__ __launch_bounds__(128) void k_gram(const float* __restrict__ M, float* __restrict__ scal)
{
  __shared__ float mi[ND];
  __shared__ float red[128];
  int i = blockIdx.x, t = threadIdx.x;
  for (int d = t; d < ND; d += 128) mi[d] = M[(size_t)i * ND + d];
  __syncthreads();
  float p = 0.f;
  if (t < 112) {
    const float* mj = M + (size_t)t * ND;
    float acc = 0.f;
    for (int d = 0; d < ND; ++d) acc += mi[d] * mj[d];
    p = acc * acc;
  }
  red[t] = p; __syncthreads();
  for (int o = 64; o > 0; o >>= 1) { if (t < o) red[t] += red[t + o]; __syncthreads(); }
  if (t == 0) atomicAdd(&scal[2], red[0]);
}

// ---------------- K4: diagsq_sum ----------------
__global__ __launch_bounds__(256) void k_diag(const float* __restrict__ M, float* __restrict__ scal)
{
  int d = blockIdx.x * 256 + threadIdx.x;
  float tsum = 0.f;
  for (int r = 0; r < 112; ++r) { float v = M[(size_t)r * ND + d]; tsum += v * v; }
  float p = tsum * tsum;
  __shared__ float red[256];
  red[threadIdx.x] = p; __syncthreads();
  for (int o = 128; o > 0; o >>= 1) { if (threadIdx.x < o) red[threadIdx.x] += red[threadIdx.x + o]; __syncthreads(); }
  if (threadIdx.x == 0) atomicAdd(&scal[3], red[0]);
}

// ---------------- K5: LayerNorm of 112 proto rows -> h_bf[8][112][1024] bf16, + raw copy ----------------
__global__ __launch_bounds__(256) void k_ln(
    const float* __restrict__ p2, const float* __restrict__ p3,
    const float* __restrict__ p4, const float* __restrict__ p5,
    const float* __restrict__ ln_g, const float* __restrict__ ln_b,
    unsigned short* __restrict__ hbf, float* __restrict__ pall)
{
  int r = blockIdx.x, t = threadIdx.x;
  const float* pp; int idx;
  if (r < 16)      { pp = p2; idx = r; }
  else if (r < 40) { pp = p3; idx = r - 16; }
  else if (r < 72) { pp = p4; idx = r - 40; }
  else             { pp = p5; idx = r - 72; }
  const float* row = pp + (size_t)idx * ND;
  __shared__ float xs[ND];
  float s1 = 0.f, s2 = 0.f;
  for (int d = t; d < ND; d += 256) { float v = row[d]; xs[d] = v; s1 += v; s2 += v * v; }
  __shared__ float ra[256], rb[256];
  ra[t] = s1; rb[t] = s2; __syncthreads();
  for (int o = 128; o > 0; o >>= 1) { if (t < o) { ra[t] += ra[t + o]; rb[t] += rb[t + o]; } __syncthreads(); }
  __shared__ float mu, rstd;
  if (t == 0) {
    float m = ra[0] * (1.f / 1024.f);
    float var = rb[0] * (1.f / 1024.f) - m * m;
    mu = m; rstd = rsqrtf(var + 1e-5f);
  }
  __syncthreads();
  for (int d = t; d < ND; d += 256) pall[(size_t)r * ND + d] = xs[d];
#pragma unroll
  for (int c = 0; c < 8; ++c)
    for (int d = t; d < ND; d += 256) {
      float h = (xs[d] - mu) * rstd * ln_g[(size_t)c * ND + d] + ln_b[(size_t)c * ND + d];
      hbf[((size_t)(c * 112 + r)) * ND + d] = f2bf(h);
    }
}

// ---------------- K6: qkv_all[c] = H_bf[c] @ W_qkv[c]^T + b, gload_lds staged ----------------
// N per block = 64, BK = 128, grid (48, 8). LDS: Wl fp32 64x128 linear (swz <<5), Hl bf16 112x128 (swz <<4).
__global__ __launch_bounds__(256) void k_qkv_mfma(
    const unsigned short* __restrict__ hbf, const float* __restrict__ w_qkv,
    const float* __restrict__ b_qkv, float* __restrict__ qkv_all)
{
  __shared__ __align__(16) float Wl[64 * 128];           // 32 KB, 512 B rows
  __shared__ __align__(16) unsigned short Hl[112 * 128]; // 28 KB, 256 B rows
  int c = blockIdx.y;
  int nb0 = blockIdx.x * 64;
  int t = threadIdx.x, lane = t & 63, wv = t >> 6;
  const float* W = w_qkv + ((size_t)c * 3072 + nb0) * ND;
  const unsigned short* H = hbf + (size_t)c * 112 * ND;

  // precompute per-lane staging sources (kt-independent part) with inverse swizzle
  const char* wsrc[8]; char* wdst[8];
#pragma unroll
  for (int j = 0; j < 8; ++j) {
    int n = (wv * 8 + j) * 2 + (lane >> 5);
    int cbs = ((lane & 31) * 16) ^ ((n & 15) << 5);
    wsrc[j] = (const char*)(W + (size_t)n * ND) + cbs;
    wdst[j] = (char*)Wl + (wv * 8 + j) * 1024;
  }
  const char* hsrc[7]; char* hdst[7];
#pragma unroll
  for (int j = 0; j < 7; ++j) {
    int r = (wv * 7 + j) * 4 + (lane >> 4);
    int cbs = ((lane & 15) * 16) ^ ((r & 15) << 4);
    hsrc[j] = (const char*)(H + (size_t)r * ND) + cbs;
    hdst[j] = (char*)Hl + (wv * 7 + j) * 1024;
  }

  f32x4 acc[7] = {};
  int r16 = lane & 15, q = lane >> 4;       // kq = q*8
  const char* wrow = (const char*)Wl + (wv * 16 + r16) * 512;
  int swq = r16 << 5, swa = r16 << 4;

  for (int kt = 0; kt < ND; kt += 128) {
    __syncthreads();
#pragma unroll
    for (int j = 0; j < 8; ++j) gl_lds16(wsrc[j] + (size_t)kt * 4, wdst[j]);
#pragma unroll
    for (int j = 0; j < 7; ++j) gl_lds16(hsrc[j] + (size_t)kt * 2, hdst[j]);
    __syncthreads();
#pragma unroll
    for (int kk4 = 0; kk4 < 4; ++kk4) {
      int cb = kk4 * 128 + q * 32;          // f32 byte offset of 8-elem k-slice
      int o = cb ^ swq;
      float4 w0 = *(const float4*)(wrow + o);
      float4 w1 = *(const float4*)(wrow + o + 16);
      bf16x8 bv;
      bv[0] = (short)f2bf(w0.x); bv[1] = (short)f2bf(w0.y);
      bv[2] = (short)f2bf(w0.z); bv[3] = (short)f2bf(w0.w);
      bv[4] = (short)f2bf(w1.x); bv[5] = (short)f2bf(w1.y);
      bv[6] = (short)f2bf(w1.z); bv[7] = (short)f2bf(w1.w);
      int oa = (kk4 * 64 + q * 16) ^ swa;   // bf16 byte offset
#pragma unroll
      for (int m = 0; m < 7; ++m) {
        bf16x8 av = *(const bf16x8*)((const char*)Hl + (m * 16 + r16) * 256 + oa);
        acc[m] = __builtin_amdgcn_mfma_f32_16x16x32_bf16(av, bv, acc[m], 0, 0, 0);
      }
    }
  }
  int col = nb0 + wv * 16 + r16;
  float bq = b_qkv[(size_t)c * 3072 + col];
  int rbase = q * 4;
#pragma unroll
  for (int m = 0; m < 7; ++m)
#pragma unroll
    for (int r = 0; r < 4; ++r)
      qkv_all[((size_t)c * 112 + m * 16 + rbase + r) * 3072 + col] = acc[m][r] + bq;
}

// ---------------- K7: attention per (head, sample); obuf written as bf16 ----------------
__global__ __launch_bounds__(256) void k_attn(
    const float* __restrict__ qkv_all, const int* __restrict__ cls,
    const int* __restrict__ rows_g, unsigned short* __restrict__ obf)
{
  __shared__ float qs[NS * NDH], ks2[NS * NDH], vs[NS * NDH];
  __shared__ float sc[NS * NS];
  __shared__ int rg[NS];
  int h = blockIdx.x, b = blockIdx.y, t = threadIdx.x;
  if (t < NS) rg[t] = rows_g[b * NS + t];
  __syncthreads();
  int cp = cls[b * 4 + 3];
  const float scale = 0.08838834764831843f;  // 128^-0.5
  for (int i = t; i < NS * NDH; i += 256) {
    int s = i >> 7, e = i & 127;
    size_t base = ((size_t)cp * 112 + rg[s]) * 3072 + h * NDH + e;
    qs[i] = qkv_all[base] * scale;
    ks2[i] = qkv_all[base + 1024];
    vs[i] = qkv_all[base + 2048];
  }
  __syncthreads();
  if (t < NS * NS) {
    int si = t / NS, sj = t % NS;
    float acc = 0.f;
    for (int e = 0; e < NDH; ++e) acc += qs[si * NDH + e] * ks2[sj * NDH + e];
    sc[t] = acc;
  }
  __syncthreads();
  if (t < NS) {
    float m = -1e30f;
    for (int j = 0; j < NS; ++j) m = fmaxf(m, sc[t * NS + j]);
    float e_[NS]; float sum = 0.f;
    for (int j = 0; j < NS; ++j) { float e = expf(sc[t * NS + j] - m); e_[j] = e; sum += e; }
    float inv = 1.f / sum;
    for (int j = 0; j < NS; ++j) sc[t * NS + j] = e_[j] * inv;
  }
  __syncthreads();
  for (int i = t; i < NS * NDH; i += 256) {
    int s = i >> 7, e = i & 127;
    float acc = 0.f;
    for (int j = 0; j < NS; ++j) acc += sc[s * NS + j] * vs[j * NDH + e];
    obf[((size_t)b * NS + s) * ND + h * NDH + e] = f2bf(acc);
  }
}

// ---------------- K8: proj, class-batched, gload_lds staged ----------------
// N per block = 64, BK = 128, grid (16, 128). A = obf bf16 gathered rows, W = w_proj fp32.
__global__ __launch_bounds__(256) void k_proj_mfma(
    const unsigned short* __restrict__ obf, const int* __restrict__ order,
    const int* __restrict__ ccnt, const int* __restrict__ rows_g,
    const float* __restrict__ w_proj, const float* __restrict__ b_proj,
    const float* __restrict__ pall, float* __restrict__ att)
{
  int c = blockIdx.y >> 4, ch = blockIdx.y & 15;
  int cnt = ccnt[c];
  int nb = cnt - ch * 8;
  if (nb <= 0) return;
  if (nb > 8) nb = 8;
  __shared__ __align__(16) float Wl[64 * 128];           // 32 KB
  __shared__ __align__(16) unsigned short Al[112 * 128]; // 28 KB
  __shared__ int sid_s[8];
  int t = threadIdx.x, lane = t & 63, wv = t >> 6;
  if (t < 8) sid_s[t] = order[c * 128 + ch * 8 + ((t < nb) ? t : 0)];
  __syncthreads();
  int nb0 = blockIdx.x * 64;
  const float* W = w_proj + ((size_t)c * ND + nb0) * ND;

  const char* wsrc[8]; char* wdst[8];
#pragma unroll
  for (int j = 0; j < 8; ++j) {
    int n = (wv * 8 + j) * 2 + (lane >> 5);
    int cbs = ((lane & 31) * 16) ^ ((n & 15) << 5);
    wsrc[j] = (const char*)(W + (size_t)n * ND) + cbs;
    wdst[j] = (char*)Wl + (wv * 8 + j) * 1024;
  }
  const char* asrc[7]; char* adst[7];
#pragma unroll
  for (int j = 0; j < 7; ++j) {
    int r = (wv * 7 + j) * 4 + (lane >> 4);
    int cbs = ((lane & 15) * 16) ^ ((r & 15) << 4);
    int si = r / 14, s = r - si * 14;
    asrc[j] = (const char*)(obf + ((size_t)sid_s[si] * NS + s) * ND) + cbs;
    adst[j] = (char*)Al + (wv * 7 + j) * 1024;
  }

  f32x4 acc[7] = {};
  int r16 = lane & 15, q = lane >> 4;
  const char* wrow = (const char*)Wl + (wv * 16 + r16) * 512;
  int swq = r16 << 5, swa = r16 << 4;

  for (int kt = 0; kt < ND; kt += 128) {
    __syncthreads();
#pragma unroll
    for (int j = 0; j < 8; ++j) gl_lds16(wsrc[j] + (size_t)kt * 4, wdst[j]);
#pragma unroll
    for (int j = 0; j < 7; ++j) gl_lds16(asrc[j] + (size_t)kt * 2, adst[j]);
    __syncthreads();
#pragma unroll
    for (int kk4 = 0; kk4 < 4; ++kk4) {
      int cb = kk4 * 128 + q * 32;
      int o = cb ^ swq;
      float4 w0 = *(const float4*)(wrow + o);
      float4 w1 = *(const float4*)(wrow + o + 16);
      bf16x8 bv;
      bv[0] = (short)f2bf(w0.x); bv[1] = (short)f2bf(w0.y);
      bv[2] = (short)f2bf(w0.z); bv[3] = (short)f2bf(w0.w);
      bv[4] = (short)f2bf(w1.x); bv[5] = (short)f2bf(w1.y);
      bv[6] = (short)f2bf(w1.z); bv[7] = (short)f2bf(w1.w);
      int oa = (kk4 * 64 + q * 16) ^ swa;
#pragma unroll
      for (int m = 0; m < 7; ++m) {
        bf16x8 av = *(const bf16x8*)((const char*)Al + (m * 16 + r16) * 256 + oa);
        acc[m] = __builtin_amdgcn_mfma_f32_16x16x32_bf16(av, bv, acc[m], 0, 0, 0);
      }
    }
  }
  int col = nb0 + wv * 16 + r16;
  float bp = b_proj[(size_t)c * ND + col];
  int rbase = q * 4;
#pragma unroll
  for (int m = 0; m < 7; ++m)
#pragma unroll
    for (int r = 0; r < 4; ++r) {
      int row = m * 16 + rbase + r;
      int si = row / 14, s = row - si * 14;
      if (si < nb) {
        int b = sid_s[si];
        float res = pall[(size_t)rows_g[b * NS + s] * ND + col];
        att[((size_t)b * NS + s) * ND + col] = acc[m][r] + bp + res;
      }
    }
}

// ---------------- K9: normalize rows, pool, logits; write vcr ----------------
__global__ __launch_bounds__(256) void k_final(
    const float* __restrict__ att, const float* __restrict__ w_cls,
    const float* __restrict__ b_cls, const float* __restrict__ scal,
    float* __restrict__ out)
{
  int b = blockIdx.x, t = threadIdx.x;
  __shared__ float red[256];
  __shared__ float inv[NS];
  __shared__ float pooled[ND];
  for (int s = 0; s < NS; ++s) {
    float p = 0.f;
    for (int d = t; d < ND; d += 256) { float v = att[((size_t)b * NS + s) * ND + d]; p += v * v; }
    red[t] = p; __syncthreads();
    for (int o = 128; o > 0; o >>= 1) { if (t < o) red[t] += red[t + o]; __syncthreads(); }
    if (t == 0) inv[s] = 1.f / fmaxf(sqrtf(red[0]), 1e-12f);
    __syncthreads();
  }
  for (int d = t; d < ND; d += 256) {
    float acc = 0.f;
    for (int s = 0; s < NS; ++s) acc += att[((size_t)b * NS + s) * ND + d] * inv[s];
    pooled[d] = acc * (1.f / 14.f);
  }
  __syncthreads();
  int c = t >> 5, lane = t & 31;
  float acc = 0.f;
  for (int d = lane; d < ND; d += 32) acc += pooled[d] * w_cls[(size_t)c * ND + d];
  for (int o = 16; o > 0; o >>= 1) acc += __shfl_down(acc, o, 32);
  if (lane == 0) out[b * 8 + c] = acc + b_cls[c];
  if (b == 0 && t == 0) {
    float repr = scal[0] * (1.f / (128.f * 4.f * 1024.f));
    float stdl = scal[1] * (1.f / 14336.f);
    float covl = (scal[2] - scal[3]) * (1.f / 1024.f);
    out[1024] = 25.f * repr + 25.f * stdl + covl;
  }
}

extern "C" void kernel_launch(void* const* d_in, const int* in_sizes, int n_in,
                              void* d_out, int out_size, void* d_ws, size_t ws_size,
                              hipStream_t stream) {
  const float* x      = (const float*)d_in[0];
  const float* p2     = (const float*)d_in[1];
  const float* p3     = (const float*)d_in[2];
  const float* p4     = (const float*)d_in[3];
  const float* p5     = (const float*)d_in[4];
  const float* ln_g   = (const float*)d_in[5];
  const float* ln_b   = (const float*)d_in[6];
  const float* w_qkv  = (const float*)d_in[7];
  const float* b_qkv  = (const float*)d_in[8];
  const float* w_proj = (const float*)d_in[9];
  const float* b_proj = (const float*)d_in[10];
  const float* w_cls  = (const float*)d_in[11];
  const float* b_cls  = (const float*)d_in[12];
  float* out = (float*)d_out;
  char* ws = (char*)d_ws;

  float* scal   = (float*)(ws + 0);            // [0]=repr [1]=std [2]=fro [3]=diagsq
  int*   counts = (int*)(ws + 64);             // [4][8]
  int*   ccnt   = (int*)(ws + 192);            // [8]
  int*   cls    = (int*)(ws + 256);            // [128][4]
  int*   rows_g = (int*)(ws + 2304);           // [128][14]
  int*   order  = (int*)(ws + 9472);           // [8][128]
  float* pall   = (float*)(ws + 16384);        // 112*1024 f32         -> 475,136
  unsigned short* hbf = (unsigned short*)(ws + 475136);   // 8*112*1024 bf16 -> 2,310,144
  float* qkv_all = (float*)(ws + 2310144);     // 8*112*3072 f32       -> 13,320,192
  unsigned short* obf = (unsigned short*)(ws + 13320192); // 128*14*1024 bf16 -> 16,990,208
  float* att    = (float*)(ws + 16990208);     // 128*14*1024 f32      -> 24,330,240
  float* M      = (float*)(ws + 24330240);     // 112*1024 f32         -> 24,788,992

  hipMemsetAsync(ws, 0, 256, stream);          // scal + counts + ccnt
  k_assign<<<128, 128, 0, stream>>>(x, p2, p3, p4, p5, cls, counts, scal, rows_g, ccnt, order);
  k_stats<<<56, 256, 0, stream>>>(p2, p3, p4, p5, counts, M, scal);
  k_gram<<<112, 128, 0, stream>>>(M, scal);
  k_diag<<<4, 256, 0, stream>>>(M, scal);
  k_ln<<<112, 256, 0, stream>>>(p2, p3, p4, p5, ln_g, ln_b, hbf, pall);
  k_qkv_mfma<<<dim3(48, 8), 256, 0, stream>>>(hbf, w_qkv, b_qkv, qkv_all);
  k_attn<<<dim3(8, 128), 256, 0, stream>>>(qkv_all, cls, rows_g, obf);
  k_proj_mfma<<<dim3(16, 128), 256, 0, stream>>>(obf, order, ccnt, rows_g, w_proj, b_proj, pall, att);
  k_final<<<128, 256, 0, stream>>>(att, w_cls, b_cls, scal, out);
}

// Round 4
// 159.947 us; speedup vs baseline: 4.1595x; 1.1104x over previous
//
#include <hip/hip_runtime.h>
#include <math.h>

#define NB 128   // batch
#define ND 1024  // embed dim
#define NS 14    // sum of K_range
#define NDH 128  // head dim

typedef float f32x4 __attribute__((ext_vector_type(4)));
typedef short bf16x8 __attribute__((ext_vector_type(8)));   // 8 bf16 in 4 VGPRs

__device__ __forceinline__ unsigned short f2bf(float v) {   // RNE, finite inputs
  unsigned int u = __builtin_bit_cast(unsigned int, v);
  return (unsigned short)((u + 0x7FFFu + ((u >> 16) & 1u)) >> 16);
}
__device__ __forceinline__ float bf2f(unsigned short u) {
  return __builtin_bit_cast(float, (unsigned int)u << 16);
}

__device__ __forceinline__ void gl_lds16(const void* g, void* l) {
  __builtin_amdgcn_global_load_lds(
      (const __attribute__((address_space(1))) void*)g,
      (__attribute__((address_space(3))) void*)l, 16, 0, 0);
}

// s in [0,14) -> group g in [0,4), k within group
__device__ __forceinline__ void s_decomp(int s, int& g, int& k) {
  if (s < 2)      { g = 0; k = s; }
  else if (s < 5) { g = 1; k = s - 2; }
  else if (s < 9) { g = 2; k = s - 5; }
  else            { g = 3; k = s - 9; }
}
__device__ __forceinline__ const float* grp_ptr(int g, const float* p2, const float* p3,
                                                const float* p4, const float* p5) {
  return g == 0 ? p2 : g == 1 ? p3 : g == 2 ? p4 : p5;
}
__device__ __forceinline__ int grp_base(int g) { return g == 0 ? 0 : g == 1 ? 16 : g == 2 ? 40 : 72; }
__device__ __forceinline__ int grp_k(int g) { return g + 2; }

// ---------------- K1: distances, argmin per group, cls, rows_g, minv (no atomics) ----------------
__global__ __launch_bounds__(128) void k_assign(
    const float* __restrict__ x,
    const float* __restrict__ p2, const float* __restrict__ p3,
    const float* __restrict__ p4, const float* __restrict__ p5,
    int* __restrict__ cls, int* __restrict__ rows_g, float* __restrict__ minv)
{
  __shared__ float xs[ND];
  __shared__ float d2s[112];
  __shared__ int cls_s[4];
  int b = blockIdx.x, t = threadIdx.x;
  float4* xs4 = (float4*)xs;
  const float4* xg4 = (const float4*)(x + (size_t)b * ND);
  for (int i = t; i < 256; i += 128) xs4[i] = xg4[i];
  __syncthreads();
  if (t < 112) {
    const float* pp; int idx;
    if (t < 16)      { pp = p2; idx = t; }
    else if (t < 40) { pp = p3; idx = t - 16; }
    else if (t < 72) { pp = p4; idx = t - 40; }
    else             { pp = p5; idx = t - 72; }
    const float4* pr4 = (const float4*)(pp + (size_t)idx * ND);
    float acc = 0.f;
#pragma unroll 8
    for (int d = 0; d < 256; ++d) {
      float4 a = xs4[d], p = pr4[d];
      float dx = a.x - p.x, dy = a.y - p.y, dz = a.z - p.z, dw = a.w - p.w;
      acc += dx * dx + dy * dy + dz * dz + dw * dw;
    }
    d2s[t] = acc;
  }
  __syncthreads();
  if (t < 4) {
    int base = grp_base(t), kg = grp_k(t), cnt = 8 * kg;
    float mv = d2s[base]; int mi = 0;
    for (int j = 1; j < cnt; ++j) { float v = d2s[base + j]; if (v < mv) { mv = v; mi = j; } }
    int c = mi / kg;
    cls[b * 4 + t] = c; cls_s[t] = c;
    minv[b * 4 + t] = mv;
  }
  __syncthreads();
  if (t < NS) {
    int g, k; s_decomp(t, g, k);
    rows_g[b * NS + t] = grp_base(g) + cls_s[g] * grp_k(g) + k;
  }
}

// ---------------- K1b: single block -- counts/ccnt/order, repr sum, zero scalars ----------------
__global__ __launch_bounds__(128) void k_prep(
    const int* __restrict__ cls, const float* __restrict__ minv,
    int* __restrict__ counts, int* __restrict__ ccnt, int* __restrict__ order,
    float* __restrict__ scal)
{
  __shared__ int cnt_s[32];
  __shared__ int cc_s[8];
  __shared__ float red[128];
  int t = threadIdx.x;
  if (t < 32) cnt_s[t] = 0;
  if (t < 8) cc_s[t] = 0;
  if (t < 4) scal[t] = 0.f;            // [0] overwritten below by t==0
  __syncthreads();
  int c3;
#pragma unroll
  for (int g = 0; g < 4; ++g) {
    int c = cls[t * 4 + g];
    atomicAdd(&cnt_s[g * 8 + c], 1);
    if (g == 3) c3 = c;
  }
  int pos = atomicAdd(&cc_s[c3], 1);
  order[c3 * 128 + pos] = t;
  red[t] = minv[t * 4 + 0] + minv[t * 4 + 1] + minv[t * 4 + 2] + minv[t * 4 + 3];
  __syncthreads();
  for (int o = 64; o > 0; o >>= 1) { if (t < o) red[t] += red[t + o]; __syncthreads(); }
  if (t == 0) scal[0] = red[0];
  if (t < 32) counts[t] = cnt_s[t];
  if (t < 8) ccnt[t] = cc_s[t];
}

// ---------------- K2: std_loss partials + M matrix (112 x 1024) ----------------
__global__ __launch_bounds__(256) void k_stats(
    const float* __restrict__ p2, const float* __restrict__ p3,
    const float* __restrict__ p4, const float* __restrict__ p5,
    const int* __restrict__ counts, float* __restrict__ M, float* __restrict__ scal)
{
  int idx = blockIdx.x * 256 + threadIdx.x;   // 56*256 = 14336 = NS*ND
  int s = idx >> 10, d = idx & 1023;
  int g, k; s_decomp(s, g, k);
  const float* pp = grp_ptr(g, p2, p3, p4, p5);
  int kg = grp_k(g);
  float vc[8], nc[8];
  float sum = 0.f, sumsq = 0.f;
#pragma unroll
  for (int c = 0; c < 8; ++c) {
    float v = pp[((size_t)(c * kg + k)) * ND + d];
    float n = (float)counts[g * 8 + c];
    vc[c] = v; nc[c] = n;
    sum += n * v; sumsq += n * v * v;
  }
  float mean = sum * (1.f / 128.f);
  float var = (sumsq - 128.f * mean * mean) * (1.f / 127.f);
  float sd = sqrtf(var + 1e-4f);
#pragma unroll
  for (int c = 0; c < 8; ++c)
    M[((size_t)(s * 8 + c)) * ND + d] = sqrtf(nc[c] * (1.f / 1791.f)) * (vc[c] - mean);
  float part = fmaxf(1.f - sd, 0.f);
  __shared__ float red[256];
  red[threadIdx.x] = part; __syncthreads();
  for (int o = 128; o > 0; o >>= 1) { if (threadIdx.x < o) red[threadIdx.x] += red[threadIdx.x + o]; __syncthreads(); }
  if (threadIdx.x == 0) atomicAdd(&scal[1], red[0]);
}

// ---------------- K3: blocks 0..111 gram rows; blocks 112..119 diag ----------------
__global__ __launch_bounds__(128) void k_gramdiag(const float* __restrict__ M, float* __restrict__ scal)
{
  __shared__ float mi[ND];
  __shared__ float red[128];
  int bid = blockIdx.x, t = threadIdx.x;
  if (bid < 112) {
    for (int d = t; d < ND; d += 128) mi[d] = M[(size_t)bid * ND + d];
    __syncthreads();
    float p = 0.f;
    if (t < 112) {
      const float* mj = M + (size_t)t * ND;
      float acc = 0.f;
      for (int d = 0; d < ND; ++d) acc += mi[d] * mj[d];
      p = acc * acc;
    }
    red[t] = p; __syncthreads();
    for (int o = 64; o > 0; o >>= 1) { if (t < o) red[t] += red[t + o]; __syncthreads(); }
    if (t == 0) atomicAdd(&scal[2], red[0]);
  } else {
    int d = (bid - 112) * 128 + t;
    float tsum = 0.f;
    for (int r = 0; r < 112; ++r) { float v = M[(size_t)r * ND + d]; tsum += v * v; }
    red[t] = tsum * tsum; __syncthreads();
    for (int o = 64; o > 0; o >>= 1) { if (t < o) red[t] += red[t + o]; __syncthreads(); }
    if (t == 0) atomicAdd(&scal[3], red[0]);
  }
}

// ---------------- K5: LayerNorm of 112 proto rows -> h_bf[8][112][1024] bf16, + raw copy ----------------
__global__ __launch_bounds__(256) void k_ln(
    const float* __restrict__ p2, const float* __restrict__ p3,
    const float* __restrict__ p4, const float* __restrict__ p5,
    const float* __restrict__ ln_g, const float* __restrict__ ln_b,
    unsigned short* __restrict__ hbf, float* __restrict__ pall)
{
  int r = blockIdx.x, t = threadIdx.x;
  const float* pp; int idx;
  if (r < 16)      { pp = p2; idx = r; }
  else if (r < 40) { pp = p3; idx = r - 16; }
  else if (r < 72) { pp = p4; idx = r - 40; }
  else             { pp = p5; idx = r - 72; }
  const float4* row4 = (const float4*)(pp + (size_t)idx * ND);
  __shared__ float xs[ND];
  float4* xs4 = (float4*)xs;
  float s1 = 0.f, s2 = 0.f;
  {
    float4 v = row4[t];   // 256 threads x 1 float4 = 1024
    xs4[t] = v;
    s1 = v.x + v.y + v.z + v.w;
    s2 = v.x * v.x + v.y * v.y + v.z * v.z + v.w * v.w;
  }
  __shared__ float ra[256], rb[256];
  ra[t] = s1; rb[t] = s2; __syncthreads();
  for (int o = 128; o > 0; o >>= 1) { if (t < o) { ra[t] += ra[t + o]; rb[t] += rb[t + o]; } __syncthreads(); }
  __shared__ float mu, rstd;
  if (t == 0) {
    float m = ra[0] * (1.f / 1024.f);
    float var = rb[0] * (1.f / 1024.f) - m * m;
    mu = m; rstd = rsqrtf(var + 1e-5f);
  }
  __syncthreads();
  ((float4*)(pall + (size_t)r * ND))[t] = xs4[t];
  float4 xv = xs4[t];
  float nx = (xv.x - mu) * rstd, ny = (xv.y - mu) * rstd,
        nz = (xv.z - mu) * rstd, nw = (xv.w - mu) * rstd;
#pragma unroll
  for (int c = 0; c < 8; ++c) {
    float4 g = ((const float4*)(ln_g + (size_t)c * ND))[t];
    float4 bb = ((const float4*)(ln_b + (size_t)c * ND))[t];
    ushort4 u;
    u.x = f2bf(nx * g.x + bb.x); u.y = f2bf(ny * g.y + bb.y);
    u.z = f2bf(nz * g.z + bb.z); u.w = f2bf(nw * g.w + bb.w);
    ((ushort4*)(hbf + ((size_t)(c * 112 + r)) * ND))[t] = u;
  }
}

// ---------------- K6: qkv_bf[c] = H_bf[c] @ W_qkv[c]^T + b (bf16 out), gload_lds staged ----------------
__global__ __launch_bounds__(256) void k_qkv_mfma(
    const unsigned short* __restrict__ hbf, const float* __restrict__ w_qkv,
    const float* __restrict__ b_qkv, unsigned short* __restrict__ qkv_bf)
{
  __shared__ __align__(16) float Wl[64 * 128];           // 32 KB, 512 B rows
  __shared__ __align__(16) unsigned short Hl[112 * 128]; // 28 KB, 256 B rows
  int c = blockIdx.y;
  int nb0 = blockIdx.x * 64;
  int t = threadIdx.x, lane = t & 63, wv = t >> 6;
  const float* W = w_qkv + ((size_t)c * 3072 + nb0) * ND;
  const unsigned short* H = hbf + (size_t)c * 112 * ND;

  const char* wsrc[8]; char* wdst[8];
#pragma unroll
  for (int j = 0; j < 8; ++j) {
    int n = (wv * 8 + j) * 2 + (lane >> 5);
    int cbs = ((lane & 31) * 16) ^ ((n & 15) << 5);
    wsrc[j] = (const char*)(W + (size_t)n * ND) + cbs;
    wdst[j] = (char*)Wl + (wv * 8 + j) * 1024;
  }
  const char* hsrc[7]; char* hdst[7];
#pragma unroll
  for (int j = 0; j < 7; ++j) {
    int r = (wv * 7 + j) * 4 + (lane >> 4);
    int cbs = ((lane & 15) * 16) ^ ((r & 15) << 4);
    hsrc[j] = (const char*)(H + (size_t)r * ND) + cbs;
    hdst[j] = (char*)Hl + (wv * 7 + j) * 1024;
  }

  f32x4 acc[7] = {};
  int r16 = lane & 15, q = lane >> 4;
  const char* wrow = (const char*)Wl + (wv * 16 + r16) * 512;
  int swq = r16 << 5, swa = r16 << 4;

  for (int kt = 0; kt < ND; kt += 128) {
    __syncthreads();
#pragma unroll
    for (int j = 0; j < 8; ++j) gl_lds16(wsrc[j] + (size_t)kt * 4, wdst[j]);
#pragma unroll
    for (int j = 0; j < 7; ++j) gl_lds16(hsrc[j] + (size_t)kt * 2, hdst[j]);
    __syncthreads();
#pragma unroll
    for (int kk4 = 0; kk4 < 4; ++kk4) {
      int o = (kk4 * 128 + q * 32) ^ swq;
      float4 w0 = *(const float4*)(wrow + o);
      float4 w1 = *(const float4*)(wrow + o + 16);
      bf16x8 bv;
      bv[0] = (short)f2bf(w0.x); bv[1] = (short)f2bf(w0.y);
      bv[2] = (short)f2bf(w0.z); bv[3] = (short)f2bf(w0.w);
      bv[4] = (short)f2bf(w1.x); bv[5] = (short)f2bf(w1.y);
      bv[6] = (short)f2bf(w1.z); bv[7] = (short)f2bf(w1.w);
      int oa = (kk4 * 64 + q * 16) ^ swa;
#pragma unroll
      for (int m = 0; m < 7; ++m) {
        bf16x8 av = *(const bf16x8*)((const char*)Hl + (m * 16 + r16) * 256 + oa);
        acc[m] = __builtin_amdgcn_mfma_f32_16x16x32_bf16(av, bv, acc[m], 0, 0, 0);
      }
    }
  }
  int col = nb0 + wv * 16 + r16;
  float bq = b_qkv[(size_t)c * 3072 + col];
  int rbase = q * 4;
#pragma unroll
  for (int m = 0; m < 7; ++m)
#pragma unroll
    for (int r = 0; r < 4; ++r)
      qkv_bf[((size_t)c * 112 + m * 16 + rbase + r) * 3072 + col] = f2bf(acc[m][r] + bq);
}

// ---------------- K7: attention per (head, sample); qkv_bf in, obf (bf16) out ----------------
__global__ __launch_bounds__(256) void k_attn(
    const unsigned short* __restrict__ qkv_bf, const int* __restrict__ cls,
    const int* __restrict__ rows_g, unsigned short* __restrict__ obf)
{
  __shared__ float qs[NS * NDH], ks2[NS * NDH], vs[NS * NDH];
  __shared__ float sc[NS * NS];
  __shared__ int rg[NS];
  int h = blockIdx.x, b = blockIdx.y, t = threadIdx.x;
  if (t < NS) rg[t] = rows_g[b * NS + t];
  __syncthreads();
  int cp = cls[b * 4 + 3];
  const float scale = 0.08838834764831843f;  // 128^-0.5
  for (int i = t; i < NS * NDH; i += 256) {
    int s = i >> 7, e = i & 127;
    size_t base = ((size_t)cp * 112 + rg[s]) * 3072 + h * NDH + e;
    qs[i] = bf2f(qkv_bf[base]) * scale;
    ks2[i] = bf2f(qkv_bf[base + 1024]);
    vs[i] = bf2f(qkv_bf[base + 2048]);
  }
  __syncthreads();
  if (t < NS * NS) {
    int si = t / NS, sj = t % NS;
    float acc = 0.f;
    for (int e = 0; e < NDH; ++e) acc += qs[si * NDH + e] * ks2[sj * NDH + e];
    sc[t] = acc;
  }
  __syncthreads();
  if (t < NS) {
    float m = -1e30f;
    for (int j = 0; j < NS; ++j) m = fmaxf(m, sc[t * NS + j]);
    float e_[NS]; float sum = 0.f;
    for (int j = 0; j < NS; ++j) { float e = expf(sc[t * NS + j] - m); e_[j] = e; sum += e; }
    float inv = 1.f / sum;
    for (int j = 0; j < NS; ++j) sc[t * NS + j] = e_[j] * inv;
  }
  __syncthreads();
  for (int i = t; i < NS * NDH; i += 256) {
    int s = i >> 7, e = i & 127;
    float acc = 0.f;
    for (int j = 0; j < NS; ++j) acc += sc[s * NS + j] * vs[j * NDH + e];
    obf[((size_t)b * NS + s) * ND + h * NDH + e] = f2bf(acc);
  }
}

// ---------------- K8: proj, class-batched, gload_lds staged ----------------
__global__ __launch_bounds__(256) void k_proj_mfma(
    const unsigned short* __restrict__ obf, const int* __restrict__ order,
    const int* __restrict__ ccnt, const int* __restrict__ rows_g,
    const float* __restrict__ w_proj, const float* __restrict__ b_proj,
    const float* __restrict__ pall, float* __restrict__ att)
{
  int c = blockIdx.y >> 4, ch = blockIdx.y & 15;
  int cnt = ccnt[c];
  int nb = cnt - ch * 8;
  if (nb <= 0) return;
  if (nb > 8) nb = 8;
  __shared__ __align__(16) float Wl[64 * 128];           // 32 KB
  __shared__ __align__(16) unsigned short Al[112 * 128]; // 28 KB
  __shared__ int sid_s[8];
  int t = threadIdx.x, lane = t & 63, wv = t >> 6;
  if (t < 8) sid_s[t] = order[c * 128 + ch * 8 + ((t < nb) ? t : 0)];
  __syncthreads();
  int nb0 = blockIdx.x * 64;
  const float* W = w_proj + ((size_t)c * ND + nb0) * ND;

  const char* wsrc[8]; char* wdst[8];
#pragma unroll
  for (int j = 0; j < 8; ++j) {
    int n = (wv * 8 + j) * 2 + (lane >> 5);
    int cbs = ((lane & 31) * 16) ^ ((n & 15) << 5);
    wsrc[j] = (const char*)(W + (size_t)n * ND) + cbs;
    wdst[j] = (char*)Wl + (wv * 8 + j) * 1024;
  }
  const char* asrc[7]; char* adst[7];
#pragma unroll
  for (int j = 0; j < 7; ++j) {
    int r = (wv * 7 + j) * 4 + (lane >> 4);
    int cbs = ((lane & 15) * 16) ^ ((r & 15) << 4);
    int si = r / 14, s = r - si * 14;
    asrc[j] = (const char*)(obf + ((size_t)sid_s[si] * NS + s) * ND) + cbs;
    adst[j] = (char*)Al + (wv * 7 + j) * 1024;
  }

  f32x4 acc[7] = {};
  int r16 = lane & 15, q = lane >> 4;
  const char* wrow = (const char*)Wl + (wv * 16 + r16) * 512;
  int swq = r16 << 5, swa = r16 << 4;

  for (int kt = 0; kt < ND; kt += 128) {
    __syncthreads();
#pragma unroll
    for (int j = 0; j < 8; ++j) gl_lds16(wsrc[j] + (size_t)kt * 4, wdst[j]);
#pragma unroll
    for (int j = 0; j < 7; ++j) gl_lds16(asrc[j] + (size_t)kt * 2, adst[j]);
    __syncthreads();
#pragma unroll
    for (int kk4 = 0; kk4 < 4; ++kk4) {
      int o = (kk4 * 128 + q * 32) ^ swq;
      float4 w0 = *(const float4*)(wrow + o);
      float4 w1 = *(const float4*)(wrow + o + 16);
      bf16x8 bv;
      bv[0] = (short)f2bf(w0.x); bv[1] = (short)f2bf(w0.y);
      bv[2] = (short)f2bf(w0.z); bv[3] = (short)f2bf(w0.w);
      bv[4] = (short)f2bf(w1.x); bv[5] = (short)f2bf(w1.y);
      bv[6] = (short)f2bf(w1.z); bv[7] = (short)f2bf(w1.w);
      int oa = (kk4 * 64 + q * 16) ^ swa;
#pragma unroll
      for (int m = 0; m < 7; ++m) {
        bf16x8 av = *(const bf16x8*)((const char*)Al + (m * 16 + r16) * 256 + oa);
        acc[m] = __builtin_amdgcn_mfma_f32_16x16x32_bf16(av, bv, acc[m], 0, 0, 0);
      }
    }
  }
  int col = nb0 + wv * 16 + r16;
  float bp = b_proj[(size_t)c * ND + col];
  int rbase = q * 4;
#pragma unroll
  for (int m = 0; m < 7; ++m)
#pragma unroll
    for (int r = 0; r < 4; ++r) {
      int row = m * 16 + rbase + r;
      int si = row / 14, s = row - si * 14;
      if (si < nb) {
        int b = sid_s[si];
        float res = pall[(size_t)rows_g[b * NS + s] * ND + col];
        att[((size_t)b * NS + s) * ND + col] = acc[m][r] + bp + res;
      }
    }
}

// ---------------- K9: normalize rows, pool, logits; write vcr ----------------
__global__ __launch_bounds__(256) void k_final(
    const float* __restrict__ att, const float* __restrict__ w_cls,
    const float* __restrict__ b_cls, const float* __restrict__ scal,
    float* __restrict__ out)
{
  int b = blockIdx.x, t = threadIdx.x;
  __shared__ float red[256];
  __shared__ float inv[NS];
  __shared__ float pooled[ND];
  for (int s = 0; s < NS; ++s) {
    float p = 0.f;
    for (int d = t; d < ND; d += 256) { float v = att[((size_t)b * NS + s) * ND + d]; p += v * v; }
    red[t] = p; __syncthreads();
    for (int o = 128; o > 0; o >>= 1) { if (t < o) red[t] += red[t + o]; __syncthreads(); }
    if (t == 0) inv[s] = 1.f / fmaxf(sqrtf(red[0]), 1e-12f);
    __syncthreads();
  }
  for (int d = t; d < ND; d += 256) {
    float acc = 0.f;
    for (int s = 0; s < NS; ++s) acc += att[((size_t)b * NS + s) * ND + d] * inv[s];
    pooled[d] = acc * (1.f / 14.f);
  }
  __syncthreads();
  int c = t >> 5, lane = t & 31;
  float acc = 0.f;
  for (int d = lane; d < ND; d += 32) acc += pooled[d] * w_cls[(size_t)c * ND + d];
  for (int o = 16; o > 0; o >>= 1) acc += __shfl_down(acc, o, 32);
  if (lane == 0) out[b * 8 + c] = acc + b_cls[c];
  if (b == 0 && t == 0) {
    float repr = scal[0] * (1.f / (128.f * 4.f * 1024.f));
    float stdl = scal[1] * (1.f / 14336.f);
    float covl = (scal[2] - scal[3]) * (1.f / 1024.f);
    out[1024] = 25.f * repr + 25.f * stdl + covl;
  }
}

extern "C" void kernel_launch(void* const* d_in, const int* in_sizes, int n_in,
                              void* d_out, int out_size, void* d_ws, size_t ws_size,
                              hipStream_t stream) {
  const float* x      = (const float*)d_in[0];
  const float* p2     = (const float*)d_in[1];
  const float* p3     = (const float*)d_in[2];
  const float* p4     = (const float*)d_in[3];
  const float* p5     = (const float*)d_in[4];
  const float* ln_g   = (const float*)d_in[5];
  const float* ln_b   = (const float*)d_in[6];
  const float* w_qkv  = (const float*)d_in[7];
  const float* b_qkv  = (const float*)d_in[8];
  const float* w_proj = (const float*)d_in[9];
  const float* b_proj = (const float*)d_in[10];
  const float* w_cls  = (const float*)d_in[11];
  const float* b_cls  = (const float*)d_in[12];
  float* out = (float*)d_out;
  char* ws = (char*)d_ws;

  float* scal   = (float*)(ws + 0);            // [0]=repr [1]=std [2]=fro [3]=diagsq
  int*   counts = (int*)(ws + 64);             // [4][8]
  int*   ccnt   = (int*)(ws + 192);            // [8]
  int*   cls    = (int*)(ws + 256);            // [128][4]
  int*   rows_g = (int*)(ws + 2304);           // [128][14]
  int*   order  = (int*)(ws + 9472);           // [8][128]
  float* minv   = (float*)(ws + 13568);        // [128][4]             -> 15,616
  float* pall   = (float*)(ws + 16384);        // 112*1024 f32         -> 475,136
  unsigned short* hbf  = (unsigned short*)(ws + 475136);   // 8*112*1024 bf16  -> 2,310,144
  unsigned short* qkvb = (unsigned short*)(ws + 2310144);  // 8*112*3072 bf16  -> 9,191,424
  unsigned short* obf  = (unsigned short*)(ws + 9191424);  // 128*14*1024 bf16 -> 12,861,440
  float* att    = (float*)(ws + 12861440);     // 128*14*1024 f32      -> 20,201,472
  float* M      = (float*)(ws + 20201472);     // 112*1024 f32         -> 20,660,224

  k_assign<<<128, 128, 0, stream>>>(x, p2, p3, p4, p5, cls, rows_g, minv);
  k_prep<<<1, 128, 0, stream>>>(cls, minv, counts, ccnt, order, scal);
  k_stats<<<56, 256, 0, stream>>>(p2, p3, p4, p5, counts, M, scal);
  k_gramdiag<<<120, 128, 0, stream>>>(M, scal);
  k_ln<<<112, 256, 0, stream>>>(p2, p3, p4, p5, ln_g, ln_b, hbf, pall);
  k_qkv_mfma<<<dim3(48, 8), 256, 0, stream>>>(hbf, w_qkv, b_qkv, qkvb);
  k_attn<<<dim3(8, 128), 256, 0, stream>>>(qkvb, cls, rows_g, obf);
  k_proj_mfma<<<dim3(16, 128), 256, 0, stream>>>(obf, order, ccnt, rows_g, w_proj, b_proj, pall, att);
  k_final<<<128, 256, 0, stream>>>(att, w_cls, b_cls, scal, out);
}

// Round 5
// 136.043 us; speedup vs baseline: 4.8904x; 1.1757x over previous
//
#include <hip/hip_runtime.h>
#include <math.h>

#define NB 128   // batch
#define ND 1024  // embed dim
#define NS 14    // sum of K_range
#define NDH 128  // head dim

typedef float f32x4 __attribute__((ext_vector_type(4)));
typedef short bf16x8 __attribute__((ext_vector_type(8)));   // 8 bf16 in 4 VGPRs

__device__ __forceinline__ unsigned short f2bf(float v) {   // RNE, finite inputs
  unsigned int u = __builtin_bit_cast(unsigned int, v);
  return (unsigned short)((u + 0x7FFFu + ((u >> 16) & 1u)) >> 16);
}
__device__ __forceinline__ float bf2f(unsigned short u) {
  return __builtin_bit_cast(float, (unsigned int)u << 16);
}

__device__ __forceinline__ void gl_lds16(const void* g, void* l) {
  __builtin_amdgcn_global_load_lds(
      (const __attribute__((address_space(1))) void*)g,
      (__attribute__((address_space(3))) void*)l, 16, 0, 0);
}

// s in [0,14) -> group g in [0,4), k within group
__device__ __forceinline__ void s_decomp(int s, int& g, int& k) {
  if (s < 2)      { g = 0; k = s; }
  else if (s < 5) { g = 1; k = s - 2; }
  else if (s < 9) { g = 2; k = s - 5; }
  else            { g = 3; k = s - 9; }
}
__device__ __forceinline__ const float* grp_ptr(int g, const float* p2, const float* p3,
                                                const float* p4, const float* p5) {
  return g == 0 ? p2 : g == 1 ? p3 : g == 2 ? p4 : p5;
}
__device__ __forceinline__ int grp_base(int g) { return g == 0 ? 0 : g == 1 ? 16 : g == 2 ? 40 : 72; }
__device__ __forceinline__ int grp_k(int g) { return g + 2; }

// ---------------- K1: fused. blocks 0..111 = LayerNorm rows; blocks 112..239 = assign ----------------
__global__ __launch_bounds__(256) void k_assign_ln(
    const float* __restrict__ x,
    const float* __restrict__ p2, const float* __restrict__ p3,
    const float* __restrict__ p4, const float* __restrict__ p5,
    const float* __restrict__ ln_g, const float* __restrict__ ln_b,
    unsigned short* __restrict__ hbf, float* __restrict__ pall,
    int* __restrict__ cls, int* __restrict__ rows_g, float* __restrict__ minv)
{
  int bid = blockIdx.x, t = threadIdx.x;
  __shared__ __align__(16) float xs[ND];
  float4* xs4 = (float4*)xs;
  if (bid < 112) {
    // ---- LayerNorm of proto row bid -> hbf[8][112][1024], + raw copy to pall ----
    int r = bid;
    const float* pp; int idx;
    if (r < 16)      { pp = p2; idx = r; }
    else if (r < 40) { pp = p3; idx = r - 16; }
    else if (r < 72) { pp = p4; idx = r - 40; }
    else             { pp = p5; idx = r - 72; }
    const float4* row4 = (const float4*)(pp + (size_t)idx * ND);
    float4 v = row4[t];
    xs4[t] = v;
    float s1 = v.x + v.y + v.z + v.w;
    float s2 = v.x * v.x + v.y * v.y + v.z * v.z + v.w * v.w;
    __shared__ float ra[256], rb[256];
    ra[t] = s1; rb[t] = s2; __syncthreads();
    for (int o = 128; o > 0; o >>= 1) { if (t < o) { ra[t] += ra[t + o]; rb[t] += rb[t + o]; } __syncthreads(); }
    __shared__ float mu, rstd;
    if (t == 0) {
      float m = ra[0] * (1.f / 1024.f);
      float var = rb[0] * (1.f / 1024.f) - m * m;
      mu = m; rstd = rsqrtf(var + 1e-5f);
    }
    __syncthreads();
    ((float4*)(pall + (size_t)r * ND))[t] = xs4[t];
    float4 xv = xs4[t];
    float nx = (xv.x - mu) * rstd, ny = (xv.y - mu) * rstd,
          nz = (xv.z - mu) * rstd, nw = (xv.w - mu) * rstd;
#pragma unroll
    for (int c = 0; c < 8; ++c) {
      float4 g = ((const float4*)(ln_g + (size_t)c * ND))[t];
      float4 bb = ((const float4*)(ln_b + (size_t)c * ND))[t];
      ushort4 u;
      u.x = f2bf(nx * g.x + bb.x); u.y = f2bf(ny * g.y + bb.y);
      u.z = f2bf(nz * g.z + bb.z); u.w = f2bf(nw * g.w + bb.w);
      ((ushort4*)(hbf + ((size_t)(c * 112 + r)) * ND))[t] = u;
    }
  } else {
    // ---- assign for sample b ----
    int b = bid - 112;
    __shared__ float d2s[112];
    __shared__ int cls_s[4];
    const float4* xg4 = (const float4*)(x + (size_t)b * ND);
    xs4[t] = xg4[t];
    __syncthreads();
    if (t < 112) {
      const float* pp; int idx;
      if (t < 16)      { pp = p2; idx = t; }
      else if (t < 40) { pp = p3; idx = t - 16; }
      else if (t < 72) { pp = p4; idx = t - 40; }
      else             { pp = p5; idx = t - 72; }
      const float4* pr4 = (const float4*)(pp + (size_t)idx * ND);
      float acc = 0.f;
#pragma unroll 8
      for (int d = 0; d < 256; ++d) {
        float4 a = xs4[d], p = pr4[d];
        float dx = a.x - p.x, dy = a.y - p.y, dz = a.z - p.z, dw = a.w - p.w;
        acc += dx * dx + dy * dy + dz * dz + dw * dw;
      }
      d2s[t] = acc;
    }
    __syncthreads();
    if (t < 4) {
      int base = grp_base(t), kg = grp_k(t), cnt = 8 * kg;
      float mv = d2s[base]; int mi = 0;
      for (int j = 1; j < cnt; ++j) { float v = d2s[base + j]; if (v < mv) { mv = v; mi = j; } }
      int c = mi / kg;
      cls[b * 4 + t] = c; cls_s[t] = c;
      minv[b * 4 + t] = mv;
    }
    __syncthreads();
    if (t < NS) {
      int g, k; s_decomp(t, g, k);
      rows_g[b * NS + t] = grp_base(g) + cls_s[g] * grp_k(g) + k;
    }
  }
}

// ---------------- K1b: single block -- counts/ccnt/order, repr sum, zero scalars ----------------
__global__ __launch_bounds__(128) void k_prep(
    const int* __restrict__ cls, const float* __restrict__ minv,
    int* __restrict__ counts, int* __restrict__ ccnt, int* __restrict__ order,
    float* __restrict__ scal)
{
  __shared__ int cnt_s[32];
  __shared__ int cc_s[8];
  __shared__ float red[128];
  int t = threadIdx.x;
  if (t < 32) cnt_s[t] = 0;
  if (t < 8) cc_s[t] = 0;
  if (t < 4) scal[t] = 0.f;
  __syncthreads();
  int c3;
#pragma unroll
  for (int g = 0; g < 4; ++g) {
    int c = cls[t * 4 + g];
    atomicAdd(&cnt_s[g * 8 + c], 1);
    if (g == 3) c3 = c;
  }
  int pos = atomicAdd(&cc_s[c3], 1);
  order[c3 * 128 + pos] = t;
  red[t] = minv[t * 4 + 0] + minv[t * 4 + 1] + minv[t * 4 + 2] + minv[t * 4 + 3];
  __syncthreads();
  for (int o = 64; o > 0; o >>= 1) { if (t < o) red[t] += red[t + o]; __syncthreads(); }
  if (t == 0) scal[0] = red[0];
  if (t < 32) counts[t] = cnt_s[t];
  if (t < 8) ccnt[t] = cc_s[t];
}

// ---------------- K2: std_loss partials + M matrix (112 x 1024) ----------------
__global__ __launch_bounds__(256) void k_stats(
    const float* __restrict__ p2, const float* __restrict__ p3,
    const float* __restrict__ p4, const float* __restrict__ p5,
    const int* __restrict__ counts, float* __restrict__ M, float* __restrict__ scal)
{
  int idx = blockIdx.x * 256 + threadIdx.x;   // 56*256 = 14336 = NS*ND
  int s = idx >> 10, d = idx & 1023;
  int g, k; s_decomp(s, g, k);
  const float* pp = grp_ptr(g, p2, p3, p4, p5);
  int kg = grp_k(g);
  float vc[8], nc[8];
  float sum = 0.f, sumsq = 0.f;
#pragma unroll
  for (int c = 0; c < 8; ++c) {
    float v = pp[((size_t)(c * kg + k)) * ND + d];
    float n = (float)counts[g * 8 + c];
    vc[c] = v; nc[c] = n;
    sum += n * v; sumsq += n * v * v;
  }
  float mean = sum * (1.f / 128.f);
  float var = (sumsq - 128.f * mean * mean) * (1.f / 127.f);
  float sd = sqrtf(var + 1e-4f);
#pragma unroll
  for (int c = 0; c < 8; ++c)
    M[((size_t)(s * 8 + c)) * ND + d] = sqrtf(nc[c] * (1.f / 1791.f)) * (vc[c] - mean);
  float part = fmaxf(1.f - sd, 0.f);
  __shared__ float red[256];
  red[threadIdx.x] = part; __syncthreads();
  for (int o = 128; o > 0; o >>= 1) { if (threadIdx.x < o) red[threadIdx.x] += red[threadIdx.x + o]; __syncthreads(); }
  if (threadIdx.x == 0) atomicAdd(&scal[1], red[0]);
}

// ---------------- K3: blocks 0..111 gram rows; blocks 112..119 diag ----------------
__global__ __launch_bounds__(128) void k_gramdiag(const float* __restrict__ M, float* __restrict__ scal)
{
  __shared__ float mi[ND];
  __shared__ float red[128];
  int bid = blockIdx.x, t = threadIdx.x;
  if (bid < 112) {
    for (int d = t; d < ND; d += 128) mi[d] = M[(size_t)bid * ND + d];
    __syncthreads();
    float p = 0.f;
    if (t < 112) {
      const float* mj = M + (size_t)t * ND;
      float acc = 0.f;
      for (int d = 0; d < ND; ++d) acc += mi[d] * mj[d];
      p = acc * acc;
    }
    red[t] = p; __syncthreads();
    for (int o = 64; o > 0; o >>= 1) { if (t < o) red[t] += red[t + o]; __syncthreads(); }
    if (t == 0) atomicAdd(&scal[2], red[0]);
  } else {
    int d = (bid - 112) * 128 + t;
    float tsum = 0.f;
    for (int r = 0; r < 112; ++r) { float v = M[(size_t)r * ND + d]; tsum += v * v; }
    red[t] = tsum * tsum; __syncthreads();
    for (int o = 64; o > 0; o >>= 1) { if (t < o) red[t] += red[t + o]; __syncthreads(); }
    if (t == 0) atomicAdd(&scal[3], red[0]);
  }
}

// ---------------- K6: qkv_bf[c] = H_bf[c] @ W_qkv[c]^T + b. N=32, BK=128, 128 thr, grid (96,8) ----------------
__global__ __launch_bounds__(128) void k_qkv_mfma(
    const unsigned short* __restrict__ hbf, const float* __restrict__ w_qkv,
    const float* __restrict__ b_qkv, unsigned short* __restrict__ qkv_bf)
{
  __shared__ __align__(16) float Wl[32 * 128];           // 16 KB, 512 B rows
  __shared__ __align__(16) unsigned short Hl[112 * 128]; // 28 KB, 256 B rows
  int c = blockIdx.y;
  int nb0 = blockIdx.x * 32;
  int t = threadIdx.x, lane = t & 63, wv = t >> 6;       // wv in {0,1}
  const float* W = w_qkv + ((size_t)c * 3072 + nb0) * ND;
  const unsigned short* H = hbf + (size_t)c * 112 * ND;

  const char* wsrc[8]; char* wdst[8];
#pragma unroll
  for (int j = 0; j < 8; ++j) {
    int n = (wv * 8 + j) * 2 + (lane >> 5);              // [0,32)
    int cbs = ((lane & 31) * 16) ^ ((n & 15) << 5);
    wsrc[j] = (const char*)(W + (size_t)n * ND) + cbs;
    wdst[j] = (char*)Wl + (wv * 8 + j) * 1024;
  }
  const char* hsrc[14]; char* hdst[14];
#pragma unroll
  for (int j = 0; j < 14; ++j) {
    int r = (wv * 14 + j) * 4 + (lane >> 4);             // [0,112)
    int cbs = ((lane & 15) * 16) ^ ((r & 15) << 4);
    hsrc[j] = (const char*)(H + (size_t)r * ND) + cbs;
    hdst[j] = (char*)Hl + (wv * 14 + j) * 1024;
  }

  f32x4 acc[7] = {};
  int r16 = lane & 15, q = lane >> 4;
  const char* wrow = (const char*)Wl + (wv * 16 + r16) * 512;
  int swq = r16 << 5, swa = r16 << 4;

  for (int kt = 0; kt < ND; kt += 128) {
    __syncthreads();
#pragma unroll
    for (int j = 0; j < 8; ++j) gl_lds16(wsrc[j] + (size_t)kt * 4, wdst[j]);
#pragma unroll
    for (int j = 0; j < 14; ++j) gl_lds16(hsrc[j] + (size_t)kt * 2, hdst[j]);
    __syncthreads();
#pragma unroll
    for (int kk4 = 0; kk4 < 4; ++kk4) {
      int o = (kk4 * 128 + q * 32) ^ swq;
      float4 w0 = *(const float4*)(wrow + o);
      float4 w1 = *(const float4*)(wrow + o + 16);
      bf16x8 bv;
      bv[0] = (short)f2bf(w0.x); bv[1] = (short)f2bf(w0.y);
      bv[2] = (short)f2bf(w0.z); bv[3] = (short)f2bf(w0.w);
      bv[4] = (short)f2bf(w1.x); bv[5] = (short)f2bf(w1.y);
      bv[6] = (short)f2bf(w1.z); bv[7] = (short)f2bf(w1.w);
      int oa = (kk4 * 64 + q * 16) ^ swa;
#pragma unroll
      for (int m = 0; m < 7; ++m) {
        bf16x8 av = *(const bf16x8*)((const char*)Hl + (m * 16 + r16) * 256 + oa);
        acc[m] = __builtin_amdgcn_mfma_f32_16x16x32_bf16(av, bv, acc[m], 0, 0, 0);
      }
    }
  }
  int col = nb0 + wv * 16 + r16;
  float bq = b_qkv[(size_t)c * 3072 + col];
  int rbase = q * 4;
#pragma unroll
  for (int m = 0; m < 7; ++m)
#pragma unroll
    for (int r = 0; r < 4; ++r)
      qkv_bf[((size_t)c * 112 + m * 16 + rbase + r) * 3072 + col] = f2bf(acc[m][r] + bq);
}

// ---------------- K7: attention per (head, sample); vectorized ----------------
__global__ __launch_bounds__(256) void k_attn(
    const unsigned short* __restrict__ qkv_bf, const int* __restrict__ cls,
    const int* __restrict__ rows_g, unsigned short* __restrict__ obf)
{
  __shared__ __align__(16) float qs[NS * NDH], ks2[NS * NDH], vs[NS * NDH];
  __shared__ float sc[NS * NS];
  __shared__ int rg[NS];
  int h = blockIdx.x, b = blockIdx.y, t = threadIdx.x;
  if (t < NS) rg[t] = rows_g[b * NS + t];
  __syncthreads();
  int cp = cls[b * 4 + 3];
  const float scale = 0.08838834764831843f;  // 128^-0.5
  for (int i = t; i < NS * 64; i += 256) {   // 896 ushort2 pairs
    int s = i >> 6, e2 = (i & 63) * 2;
    size_t base = ((size_t)cp * 112 + rg[s]) * 3072 + h * NDH + e2;
    unsigned int uq = *(const unsigned int*)&qkv_bf[base];
    unsigned int uk = *(const unsigned int*)&qkv_bf[base + 1024];
    unsigned int uv = *(const unsigned int*)&qkv_bf[base + 2048];
    qs[s * NDH + e2]      = bf2f((unsigned short)uq) * scale;
    qs[s * NDH + e2 + 1]  = bf2f((unsigned short)(uq >> 16)) * scale;
    ks2[s * NDH + e2]     = bf2f((unsigned short)uk);
    ks2[s * NDH + e2 + 1] = bf2f((unsigned short)(uk >> 16));
    vs[s * NDH + e2]      = bf2f((unsigned short)uv);
    vs[s * NDH + e2 + 1]  = bf2f((unsigned short)(uv >> 16));
  }
  __syncthreads();
  if (t < NS * NS) {
    int si = t / NS, sj = t - (t / NS) * NS;
    const float4* qa = (const float4*)&qs[si * NDH];
    const float4* kb = (const float4*)&ks2[sj * NDH];
    float acc = 0.f;
#pragma unroll 8
    for (int e4 = 0; e4 < 32; ++e4) {
      float4 a = qa[e4], k4 = kb[e4];
      acc += a.x * k4.x + a.y * k4.y + a.z * k4.z + a.w * k4.w;
    }
    sc[t] = acc;
  }
  __syncthreads();
  if (t < NS) {
    float m = -1e30f;
    for (int j = 0; j < NS; ++j) m = fmaxf(m, sc[t * NS + j]);
    float e_[NS]; float sum = 0.f;
    for (int j = 0; j < NS; ++j) { float e = expf(sc[t * NS + j] - m); e_[j] = e; sum += e; }
    float inv = 1.f / sum;
    for (int j = 0; j < NS; ++j) sc[t * NS + j] = e_[j] * inv;
  }
  __syncthreads();
  for (int i = t; i < NS * 32; i += 256) {   // 448 float4 outputs
    int s = i >> 5, e4 = i & 31;
    float4 a = {0.f, 0.f, 0.f, 0.f};
#pragma unroll
    for (int j = 0; j < NS; ++j) {
      float w = sc[s * NS + j];
      float4 v4 = ((const float4*)&vs[j * NDH])[e4];
      a.x += w * v4.x; a.y += w * v4.y; a.z += w * v4.z; a.w += w * v4.w;
    }
    ushort4 u; u.x = f2bf(a.x); u.y = f2bf(a.y); u.z = f2bf(a.z); u.w = f2bf(a.w);
    ((ushort4*)&obf[((size_t)b * NS + s) * ND + h * NDH])[e4] = u;
  }
}

// ---------------- K8: proj, class-batched chunk=16 (M=224), N=32, 256 thr, grid (32,64) ----------------
__global__ __launch_bounds__(256) void k_proj_mfma(
    const unsigned short* __restrict__ obf, const int* __restrict__ order,
    const int* __restrict__ ccnt, const int* __restrict__ rows_g,
    const float* __restrict__ w_proj, const float* __restrict__ b_proj,
    const float* __restrict__ pall, float* __restrict__ att)
{
  int c = blockIdx.y >> 3, ch = blockIdx.y & 7;
  int cnt = ccnt[c];
  int nb = cnt - ch * 16;
  if (nb <= 0) return;
  if (nb > 16) nb = 16;
  __shared__ __align__(16) float Wl[32 * 128];           // 16 KB
  __shared__ __align__(16) unsigned short Al[224 * 128]; // 56 KB
  __shared__ int sid_s[16];
  int t = threadIdx.x, lane = t & 63, wv = t >> 6;
  if (t < 16) sid_s[t] = order[c * 128 + ch * 16 + ((t < nb) ? t : 0)];
  __syncthreads();
  int nb0 = blockIdx.x * 32;
  const float* W = w_proj + ((size_t)c * ND + nb0) * ND;

  const char* wsrc[4]; char* wdst[4];
#pragma unroll
  for (int j = 0; j < 4; ++j) {
    int n = (wv * 4 + j) * 2 + (lane >> 5);              // [0,32)
    int cbs = ((lane & 31) * 16) ^ ((n & 15) << 5);
    wsrc[j] = (const char*)(W + (size_t)n * ND) + cbs;
    wdst[j] = (char*)Wl + (wv * 4 + j) * 1024;
  }
  const char* asrc[14]; char* adst[14];
#pragma unroll
  for (int j = 0; j < 14; ++j) {
    int r = (wv * 14 + j) * 4 + (lane >> 4);             // [0,224)
    int cbs = ((lane & 15) * 16) ^ ((r & 15) << 4);
    int si = r / 14, s = r - si * 14;
    asrc[j] = (const char*)(obf + ((size_t)sid_s[si] * NS + s) * ND) + cbs;
    adst[j] = (char*)Al + (wv * 14 + j) * 1024;
  }

  f32x4 acc[7] = {};
  int r16 = lane & 15, q = lane >> 4;
  int colh = wv & 1, rowh = wv >> 1;
  const char* wrow = (const char*)Wl + (colh * 16 + r16) * 512;
  int swq = r16 << 5, swa = r16 << 4;

  for (int kt = 0; kt < ND; kt += 128) {
    __syncthreads();
#pragma unroll
    for (int j = 0; j < 4; ++j) gl_lds16(wsrc[j] + (size_t)kt * 4, wdst[j]);
#pragma unroll
    for (int j = 0; j < 14; ++j) gl_lds16(asrc[j] + (size_t)kt * 2, adst[j]);
    __syncthreads();
#pragma unroll
    for (int kk4 = 0; kk4 < 4; ++kk4) {
      int o = (kk4 * 128 + q * 32) ^ swq;
      float4 w0 = *(const float4*)(wrow + o);
      float4 w1 = *(const float4*)(wrow + o + 16);
      bf16x8 bv;
      bv[0] = (short)f2bf(w0.x); bv[1] = (short)f2bf(w0.y);
      bv[2] = (short)f2bf(w0.z); bv[3] = (short)f2bf(w0.w);
      bv[4] = (short)f2bf(w1.x); bv[5] = (short)f2bf(w1.y);
      bv[6] = (short)f2bf(w1.z); bv[7] = (short)f2bf(w1.w);
      int oa = (kk4 * 64 + q * 16) ^ swa;
#pragma unroll
      for (int m = 0; m < 7; ++m) {
        int row = rowh * 112 + m * 16 + r16;
        bf16x8 av = *(const bf16x8*)((const char*)Al + row * 256 + oa);
        acc[m] = __builtin_amdgcn_mfma_f32_16x16x32_bf16(av, bv, acc[m], 0, 0, 0);
      }
    }
  }
  int col = nb0 + colh * 16 + r16;
  float bp = b_proj[(size_t)c * ND + col];
  int rbase = q * 4;
#pragma unroll
  for (int m = 0; m < 7; ++m)
#pragma unroll
    for (int r = 0; r < 4; ++r) {
      int row = rowh * 112 + m * 16 + rbase + r;
      int si = row / 14, s = row - si * 14;
      if (si < nb) {
        int b = sid_s[si];
        float res = pall[(size_t)rows_g[b * NS + s] * ND + col];
        att[((size_t)b * NS + s) * ND + col] = acc[m][r] + bp + res;
      }
    }
}

// ---------------- K9: single-pass normalize+pool+logits from LDS tile; write vcr ----------------
__global__ __launch_bounds__(256) void k_final(
    const float* __restrict__ att, const float* __restrict__ w_cls,
    const float* __restrict__ b_cls, const float* __restrict__ scal,
    float* __restrict__ out)
{
  int b = blockIdx.x, t = threadIdx.x;
  __shared__ __align__(16) float as[NS * ND];   // 56 KB
  __shared__ float wred[NS][4];
  __shared__ float inv[NS];
  __shared__ __align__(16) float pooled[ND];
  int lane = t & 63, w = t >> 6;
#pragma unroll
  for (int s = 0; s < NS; ++s) {
    float4 v = ((const float4*)(att + ((size_t)b * NS + s) * ND))[t];
    ((float4*)&as[s * ND])[t] = v;
    float p = v.x * v.x + v.y * v.y + v.z * v.z + v.w * v.w;
#pragma unroll
    for (int o = 32; o > 0; o >>= 1) p += __shfl_xor(p, o, 64);
    if (lane == 0) wred[s][w] = p;
  }
  __syncthreads();
  if (t < NS) {
    float s2 = wred[t][0] + wred[t][1] + wred[t][2] + wred[t][3];
    inv[t] = 1.f / fmaxf(sqrtf(s2), 1e-12f);
  }
  __syncthreads();
  float4 pa = {0.f, 0.f, 0.f, 0.f};
#pragma unroll
  for (int s = 0; s < NS; ++s) {
    float iv = inv[s];
    float4 v = ((const float4*)&as[s * ND])[t];
    pa.x += iv * v.x; pa.y += iv * v.y; pa.z += iv * v.z; pa.w += iv * v.w;
  }
  const float k14 = 1.f / 14.f;
  pa.x *= k14; pa.y *= k14; pa.z *= k14; pa.w *= k14;
  ((float4*)pooled)[t] = pa;
  __syncthreads();
  int c = t >> 5, l = t & 31;
  float acc = 0.f;
#pragma unroll
  for (int k = 0; k < 8; ++k) {
    int i4 = l + k * 32;
    float4 p4 = ((const float4*)pooled)[i4];
    float4 wc = ((const float4*)(w_cls + (size_t)c * ND))[i4];
    acc += p4.x * wc.x + p4.y * wc.y + p4.z * wc.z + p4.w * wc.w;
  }
  for (int o = 16; o > 0; o >>= 1) acc += __shfl_down(acc, o, 32);
  if (l == 0) out[b * 8 + c] = acc + b_cls[c];
  if (b == 0 && t == 0) {
    float repr = scal[0] * (1.f / (128.f * 4.f * 1024.f));
    float stdl = scal[1] * (1.f / 14336.f);
    float covl = (scal[2] - scal[3]) * (1.f / 1024.f);
    out[1024] = 25.f * repr + 25.f * stdl + covl;
  }
}

extern "C" void kernel_launch(void* const* d_in, const int* in_sizes, int n_in,
                              void* d_out, int out_size, void* d_ws, size_t ws_size,
                              hipStream_t stream) {
  const float* x      = (const float*)d_in[0];
  const float* p2     = (const float*)d_in[1];
  const float* p3     = (const float*)d_in[2];
  const float* p4     = (const float*)d_in[3];
  const float* p5     = (const float*)d_in[4];
  const float* ln_g   = (const float*)d_in[5];
  const float* ln_b   = (const float*)d_in[6];
  const float* w_qkv  = (const float*)d_in[7];
  const float* b_qkv  = (const float*)d_in[8];
  const float* w_proj = (const float*)d_in[9];
  const float* b_proj = (const float*)d_in[10];
  const float* w_cls  = (const float*)d_in[11];
  const float* b_cls  = (const float*)d_in[12];
  float* out = (float*)d_out;
  char* ws = (char*)d_ws;

  float* scal   = (float*)(ws + 0);            // [0]=repr [1]=std [2]=fro [3]=diagsq
  int*   counts = (int*)(ws + 64);             // [4][8]
  int*   ccnt   = (int*)(ws + 192);            // [8]
  int*   cls    = (int*)(ws + 256);            // [128][4]
  int*   rows_g = (int*)(ws + 2304);           // [128][14]
  int*   order  = (int*)(ws + 9472);           // [8][128]
  float* minv   = (float*)(ws + 13568);        // [128][4]
  float* pall   = (float*)(ws + 16384);        // 112*1024 f32         -> 475,136
  unsigned short* hbf  = (unsigned short*)(ws + 475136);   // 8*112*1024 bf16  -> 2,310,144
  unsigned short* qkvb = (unsigned short*)(ws + 2310144);  // 8*112*3072 bf16  -> 9,191,424
  unsigned short* obf  = (unsigned short*)(ws + 9191424);  // 128*14*1024 bf16 -> 12,861,440
  float* att    = (float*)(ws + 12861440);     // 128*14*1024 f32      -> 20,201,472
  float* M      = (float*)(ws + 20201472);     // 112*1024 f32         -> 20,660,224

  k_assign_ln<<<240, 256, 0, stream>>>(x, p2, p3, p4, p5, ln_g, ln_b, hbf, pall, cls, rows_g, minv);
  k_qkv_mfma<<<dim3(96, 8), 128, 0, stream>>>(hbf, w_qkv, b_qkv, qkvb);
  k_prep<<<1, 128, 0, stream>>>(cls, minv, counts, ccnt, order, scal);
  k_stats<<<56, 256, 0, stream>>>(p2, p3, p4, p5, counts, M, scal);
  k_gramdiag<<<120, 128, 0, stream>>>(M, scal);
  k_attn<<<dim3(8, 128), 256, 0, stream>>>(qkvb, cls, rows_g, obf);
  k_proj_mfma<<<dim3(32, 64), 256, 0, stream>>>(obf, order, ccnt, rows_g, w_proj, b_proj, pall, att);
  k_final<<<128, 256, 0, stream>>>(att, w_cls, b_cls, scal, out);
}